// Round 2
// baseline (2112.665 us; speedup 1.0000x reference)
//
#include <hip/hip_runtime.h>
#include <hip/hip_bf16.h>

#define DEV __device__ __forceinline__

// ---------- bf16 helpers (bit-level) ----------
DEV float bfu_lo(unsigned int u) { return __uint_as_float(u << 16); }
DEV float bfu_hi(unsigned int u) { return __uint_as_float(u & 0xffff0000u); }
DEV unsigned short f2bf(float f) {
    union { float f; unsigned int u; } cv; cv.f = f;
    unsigned int u = cv.u;
    unsigned int r = (u + 0x7fffu + ((u >> 16) & 1u)) >> 16;  // RNE
    return (unsigned short)r;
}
DEV unsigned int pack2(float a, float b) {
    return (unsigned int)f2bf(a) | ((unsigned int)f2bf(b) << 16);
}
DEV void unpack8(uint4 u, float* f) {
    f[0] = bfu_lo(u.x); f[1] = bfu_hi(u.x);
    f[2] = bfu_lo(u.y); f[3] = bfu_hi(u.y);
    f[4] = bfu_lo(u.z); f[5] = bfu_hi(u.z);
    f[6] = bfu_lo(u.w); f[7] = bfu_hi(u.w);
}

// dims: B=16 N=32 D=64 H=8 S=8 LT=128 DE=256 L=16
// BN=512 BH=128 NS=256 DL=1024 DQKV=1536

// ---------- GroupNorm stats: per-scene per-channel scale a, offset b2 ----------
// grid 512, block 256
__global__ __launch_bounds__(256) void gnstats_kernel(const float* __restrict__ src,
    const float* __restrict__ gamma, const float* __restrict__ beta,
    float* __restrict__ sa, float* __restrict__ sb)
{
    __shared__ float gsum[8], gsq[8];
    const int s = blockIdx.x, tid = threadIdx.x;
    const int g = tid >> 5, il = tid & 31;
    const float* p = src + (size_t)s * 8192 + g * 1024 + il;
    float sm = 0.f, sq = 0.f;
    #pragma unroll
    for (int m = 0; m < 32; ++m) {
        float v = p[m * 32];
        sm += v; sq += v * v;
    }
    #pragma unroll
    for (int m = 16; m; m >>= 1) { sm += __shfl_xor(sm, m); sq += __shfl_xor(sq, m); }
    if (il == 0) { gsum[g] = sm; gsq[g] = sq; }
    __syncthreads();
    if (tid < 64) {
        int gg = tid >> 3;
        float mu = gsum[gg] * (1.f / 1024.f);
        float var = gsq[gg] * (1.f / 1024.f) - mu * mu;
        float a = gamma[tid] * rsqrtf(var + 1e-5f);
        sa[s * 64 + tid] = a;
        sb[s * 64 + tid] = beta[tid] - mu * a;
    }
}

// ---------- QKV conv (Cin=64,K=3) + GN applied on the fly + rearrange ----------
// grid (24, CH*32), block 128. chunk of 64 couts (one (t,h)); thread = 4 couts x 16 lt
__global__ __launch_bounds__(128) void conv_qkv_kernel(const float* __restrict__ x,
    const float* __restrict__ sa, const float* __restrict__ sb,
    const float* __restrict__ w, const float* __restrict__ bias,
    unsigned short* __restrict__ qb, unsigned short* __restrict__ kb,
    unsigned short* __restrict__ vb, int b0)
{
    __shared__ __align__(16) float sxp[64][132];      // data at cols [1..128], zero pad
    __shared__ __align__(16) unsigned short so[8][1024];
    const int chunk = blockIdx.x, sl = blockIdx.y, tid = threadIdx.x;
    const int bn = b0 * 32 + sl;
    for (int idx = tid; idx < 64 * 132; idx += 128) {
        int r = idx / 132, c = idx - r * 132;
        float v = 0.f;
        if (c >= 1 && c <= 128)
            v = x[(size_t)bn * 8192 + r * 128 + (c - 1)] * sa[bn * 64 + r] + sb[bn * 64 + r];
        sxp[r][c] = v;
    }
    __syncthreads();
    const int cog = tid >> 3, c16 = tid & 7, p0 = c16 * 16;
    const int c0 = chunk * 64 + cog * 4;
    float acc[4][16];
    #pragma unroll
    for (int a = 0; a < 4; ++a) {
        #pragma unroll
        for (int l = 0; l < 16; ++l) acc[a][l] = 0.f;
    }
    for (int cin = 0; cin < 64; ++cin) {
        float xw[20];
        const float4* row4 = (const float4*)&sxp[cin][p0];
        #pragma unroll
        for (int k = 0; k < 5; ++k) {
            float4 t = row4[k];
            xw[k*4+0] = t.x; xw[k*4+1] = t.y; xw[k*4+2] = t.z; xw[k*4+3] = t.w;
        }
        #pragma unroll
        for (int a = 0; a < 4; ++a) {
            const float* wr = w + ((size_t)(c0 + a) * 64 + cin) * 3;
            float w0 = wr[0], w1 = wr[1], w2 = wr[2];
            #pragma unroll
            for (int l = 0; l < 16; ++l)
                acc[a][l] = fmaf(w0, xw[l], fmaf(w1, xw[l+1], fmaf(w2, xw[l+2], acc[a][l])));
        }
    }
    #pragma unroll
    for (int a = 0; a < 4; ++a) {
        float bv = bias[c0 + a];
        int dl = (cog * 4 + a) * 16;        // d_local*16
        #pragma unroll
        for (int l = 0; l < 16; ++l) {
            int lt = p0 + l;
            so[lt & 7][dl + (lt >> 3)] = f2bf(acc[a][l] + bv);
        }
    }
    __syncthreads();
    const int t = chunk >> 3, h = chunk & 7;
    const int bl = sl >> 5, n = sl & 31;
    unsigned short* dst = (t == 0) ? qb : ((t == 1) ? kb : vb);
    size_t base = ((size_t)((bl * 8 + h) * 256 + n * 8)) * 1024;
    const uint4* sop = (const uint4*)&so[0][0];
    for (int idx = tid; idx < 1024; idx += 128)
        *(uint4*)(dst + base + (size_t)idx * 8) = sop[idx];
}

// ---------- token norms |q|^2, |k|^2 (chunk-local) ----------
__global__ __launch_bounds__(256) void norm_kernel(const unsigned short* __restrict__ qb,
    const unsigned short* __restrict__ kb, float* __restrict__ nq, float* __restrict__ nk)
{
    const int tok = blockIdx.x * 4 + (threadIdx.x >> 6);
    const int lane = threadIdx.x & 63;
    const unsigned short* src = blockIdx.y ? kb : qb;
    float* dst = blockIdx.y ? nk : nq;
    const uint4* p = (const uint4*)(src + (size_t)tok * 1024 + lane * 16);
    float s = 0.f;
    #pragma unroll
    for (int r = 0; r < 2; ++r) {
        float f[8]; unpack8(p[r], f);
        #pragma unroll
        for (int e = 0; e < 8; ++e) s = fmaf(f[e], f[e], s);
    }
    #pragma unroll
    for (int m = 32; m; m >>= 1) s += __shfl_xor(s, m);
    if (lane == 0) dst[tok] = s;
}

// ---------- W = 1/dist(q,k): 64x64 tile, 4x4 per thread (chunk-local bh) ----------
// grid (4,4,CH*8) block 256
__global__ __launch_bounds__(256) void attnw_kernel(const unsigned short* __restrict__ qb,
    const unsigned short* __restrict__ kb, const float* __restrict__ nq,
    const float* __restrict__ nk, unsigned short* __restrict__ attn)
{
    __shared__ __align__(16) unsigned short q_s[64][136];
    __shared__ __align__(16) unsigned short k_s[64][136];
    const int bh = blockIdx.z;
    const int i0 = blockIdx.y * 64, j0 = blockIdx.x * 64;
    const int tid = threadIdx.x, ig = tid >> 4, jg = tid & 15;
    float acc[4][4];
    #pragma unroll
    for (int a = 0; a < 4; ++a) {
        #pragma unroll
        for (int c = 0; c < 4; ++c) acc[a][c] = 0.f;
    }
    const size_t tbase = (size_t)bh * 262144;
    for (int fc = 0; fc < 8; ++fc) {
        __syncthreads();
        for (int idx = tid; idx < 1024; idx += 256) {
            int r = idx >> 4, c8 = (idx & 15) * 8;
            *(uint4*)&q_s[r][c8] = *(const uint4*)(qb + tbase + (size_t)(i0 + r) * 1024 + fc * 128 + c8);
            *(uint4*)&k_s[r][c8] = *(const uint4*)(kb + tbase + (size_t)(j0 + r) * 1024 + fc * 128 + c8);
        }
        __syncthreads();
        for (int fs = 0; fs < 16; ++fs) {
            float qf[4][8];
            #pragma unroll
            for (int ii = 0; ii < 4; ++ii) unpack8(*(const uint4*)&q_s[ig * 4 + ii][fs * 8], qf[ii]);
            #pragma unroll
            for (int jj = 0; jj < 4; ++jj) {
                float kf[8];
                unpack8(*(const uint4*)&k_s[jg + 16 * jj][fs * 8], kf);
                #pragma unroll
                for (int ii = 0; ii < 4; ++ii) {
                    #pragma unroll
                    for (int e = 0; e < 8; ++e)
                        acc[ii][jj] = fmaf(qf[ii][e], kf[e], acc[ii][jj]);
                }
            }
        }
    }
    float nqv[4], nkv[4];
    #pragma unroll
    for (int ii = 0; ii < 4; ++ii) nqv[ii] = nq[bh * 256 + i0 + ig * 4 + ii];
    #pragma unroll
    for (int jj = 0; jj < 4; ++jj) nkv[jj] = nk[bh * 256 + j0 + jg + 16 * jj];
    __syncthreads();
    #pragma unroll
    for (int ii = 0; ii < 4; ++ii) {
        #pragma unroll
        for (int jj = 0; jj < 4; ++jj) {
            float sq = nqv[ii] + nkv[jj] - 2.f * acc[ii][jj];
            q_s[ig * 4 + ii][jg + 16 * jj] = f2bf(rsqrtf(fmaxf(sq, 1e-12f)));
        }
    }
    __syncthreads();
    for (int idx = tid; idx < 4096; idx += 256) {
        int r = idx >> 6, c = idx & 63;
        attn[(size_t)bh * 65536 + (size_t)(i0 + r) * 256 + j0 + c] = q_s[r][c];
    }
}

// ---------- out = W @ V : tile 64i x 128f, 4x8 per thread (chunk-local bh) ----------
// grid (8,4,CH*8) block 256
__global__ __launch_bounds__(256) void pv_kernel(const unsigned short* __restrict__ attn,
    const unsigned short* __restrict__ vb, unsigned short* __restrict__ outb)
{
    __shared__ __align__(16) unsigned short w_s[64][72];
    __shared__ __align__(16) unsigned short v_s[64][136];
    const int bh = blockIdx.z, i0 = blockIdx.y * 64, f0 = blockIdx.x * 128;
    const int tid = threadIdx.x, ig = tid >> 4, fg = tid & 15;
    float acc[4][8];
    #pragma unroll
    for (int a = 0; a < 4; ++a) {
        #pragma unroll
        for (int e = 0; e < 8; ++e) acc[a][e] = 0.f;
    }
    for (int jc = 0; jc < 4; ++jc) {
        __syncthreads();
        for (int idx = tid; idx < 512; idx += 256) {
            int r = idx >> 3, c8 = (idx & 7) * 8;
            *(uint4*)&w_s[r][c8] = *(const uint4*)(attn + (size_t)bh * 65536 + (size_t)(i0 + r) * 256 + jc * 64 + c8);
        }
        for (int idx = tid; idx < 1024; idx += 256) {
            int r = idx >> 4, c8 = (idx & 15) * 8;
            *(uint4*)&v_s[r][c8] = *(const uint4*)(vb + (size_t)bh * 262144 + (size_t)(jc * 64 + r) * 1024 + f0 + c8);
        }
        __syncthreads();
        for (int js = 0; js < 8; ++js) {
            float wf[4][8];
            #pragma unroll
            for (int ii = 0; ii < 4; ++ii) unpack8(*(const uint4*)&w_s[ig * 4 + ii][js * 8], wf[ii]);
            #pragma unroll
            for (int jj = 0; jj < 8; ++jj) {
                float vf[8];
                unpack8(*(const uint4*)&v_s[js * 8 + jj][fg * 8], vf);
                #pragma unroll
                for (int ii = 0; ii < 4; ++ii) {
                    #pragma unroll
                    for (int e = 0; e < 8; ++e)
                        acc[ii][e] = fmaf(wf[ii][jj], vf[e], acc[ii][e]);
                }
            }
        }
    }
    #pragma unroll
    for (int ii = 0; ii < 4; ++ii) {
        uint4 o;
        o.x = pack2(acc[ii][0], acc[ii][1]);
        o.y = pack2(acc[ii][2], acc[ii][3]);
        o.z = pack2(acc[ii][4], acc[ii][5]);
        o.w = pack2(acc[ii][6], acc[ii][7]);
        *(uint4*)(outb + (size_t)bh * 262144 + (size_t)(i0 + ig * 4 + ii) * 1024 + f0 + fg * 8) = o;
    }
}

// ---------- merge conv (Cin=512,K=3) from rearranged out + residual -> x2 ----------
// grid CH*32 block 128; cin chunks of 128; data at cols [2..129]
__global__ __launch_bounds__(128) void merge_kernel(const unsigned short* __restrict__ outb,
    const float* __restrict__ x, const float* __restrict__ w,
    const float* __restrict__ bias, float* __restrict__ x2, int b0)
{
    __shared__ __align__(16) unsigned short in_s[128][136];
    const int sl = blockIdx.x, tid = threadIdx.x;
    const int bn = b0 * 32 + sl;
    const int bl = sl >> 5, n = sl & 31;
    const int cog = tid >> 3, c16 = tid & 7, p0 = c16 * 16;
    float acc[4][16];
    #pragma unroll
    for (int a = 0; a < 4; ++a) {
        #pragma unroll
        for (int l = 0; l < 16; ++l) acc[a][l] = 0.f;
    }
    for (int ch = 0; ch < 4; ++ch) {
        __syncthreads();
        in_s[tid][0] = 0; in_s[tid][1] = 0; in_s[tid][130] = 0; in_s[tid][131] = 0;
        for (int idx = tid; idx < 16384; idx += 128) {
            int hh = idx >> 13, rem = idx & 8191;
            int st = rem >> 10, feat = rem & 1023;
            int d = feat >> 4, l = feat & 15;
            in_s[hh * 64 + d][2 + l * 8 + st] =
                outb[((size_t)((bl * 8 + ch * 2 + hh) * 256 + n * 8 + st)) * 1024 + feat];
        }
        __syncthreads();
        for (int cl = 0; cl < 128; ++cl) {
            int cin = ch * 128 + cl;
            float xw[24];
            const uint4* rp = (const uint4*)&in_s[cl][p0];
            #pragma unroll
            for (int k3 = 0; k3 < 3; ++k3) unpack8(rp[k3], &xw[k3 * 8]);
            #pragma unroll
            for (int a = 0; a < 4; ++a) {
                const float* wr = w + ((size_t)(cog * 4 + a) * 512 + cin) * 3;
                float w0 = wr[0], w1 = wr[1], w2 = wr[2];
                #pragma unroll
                for (int l = 0; l < 16; ++l)
                    acc[a][l] = fmaf(w0, xw[l+1], fmaf(w1, xw[l+2], fmaf(w2, xw[l+3], acc[a][l])));
            }
        }
    }
    #pragma unroll
    for (int a = 0; a < 4; ++a) {
        int c = cog * 4 + a;
        float bv = bias[c];
        const float4* xi = (const float4*)(x + (size_t)bn * 8192 + c * 128 + p0);
        float4* xo = (float4*)(x2 + (size_t)bn * 8192 + c * 128 + p0);
        #pragma unroll
        for (int k = 0; k < 4; ++k) {
            float4 xv = xi[k];
            float4 o;
            o.x = acc[a][k*4+0] + bv + xv.x;
            o.y = acc[a][k*4+1] + bv + xv.y;
            o.z = acc[a][k*4+2] + bv + xv.z;
            o.w = acc[a][k*4+3] + bv + xv.w;
            xo[k] = o;
        }
    }
}

// ---------- ff1 conv (Cin=64 -> 256) with GN2 on the fly + swish -> h bf16 ----------
// grid (4, 512) block 128
__global__ __launch_bounds__(128) void ff1_kernel(const float* __restrict__ x2,
    const float* __restrict__ sa, const float* __restrict__ sb,
    const float* __restrict__ w, const float* __restrict__ bias,
    unsigned short* __restrict__ hb)
{
    __shared__ __align__(16) float sxp[64][132];
    const int chunk = blockIdx.x, bn = blockIdx.y, tid = threadIdx.x;
    for (int idx = tid; idx < 64 * 132; idx += 128) {
        int r = idx / 132, c = idx - r * 132;
        float v = 0.f;
        if (c >= 1 && c <= 128)
            v = x2[(size_t)bn * 8192 + r * 128 + (c - 1)] * sa[bn * 64 + r] + sb[bn * 64 + r];
        sxp[r][c] = v;
    }
    __syncthreads();
    const int cog = tid >> 3, c16 = tid & 7, p0 = c16 * 16;
    const int c0 = chunk * 64 + cog * 4;
    float acc[4][16];
    #pragma unroll
    for (int a = 0; a < 4; ++a) {
        #pragma unroll
        for (int l = 0; l < 16; ++l) acc[a][l] = 0.f;
    }
    for (int cin = 0; cin < 64; ++cin) {
        float xw[20];
        const float4* row4 = (const float4*)&sxp[cin][p0];
        #pragma unroll
        for (int k = 0; k < 5; ++k) {
            float4 t = row4[k];
            xw[k*4+0] = t.x; xw[k*4+1] = t.y; xw[k*4+2] = t.z; xw[k*4+3] = t.w;
        }
        #pragma unroll
        for (int a = 0; a < 4; ++a) {
            const float* wr = w + ((size_t)(c0 + a) * 64 + cin) * 3;
            float w0 = wr[0], w1 = wr[1], w2 = wr[2];
            #pragma unroll
            for (int l = 0; l < 16; ++l)
                acc[a][l] = fmaf(w0, xw[l], fmaf(w1, xw[l+1], fmaf(w2, xw[l+2], acc[a][l])));
        }
    }
    #pragma unroll
    for (int a = 0; a < 4; ++a) {
        int c = c0 + a;
        float bv = bias[c];
        unsigned short* op = hb + (size_t)bn * 32768 + (size_t)c * 128 + p0;
        #pragma unroll
        for (int l2 = 0; l2 < 8; ++l2) {
            float t0 = acc[a][l2*2]   + bv; float s0 = t0 / (1.f + __expf(-t0));
            float t1 = acc[a][l2*2+1] + bv; float s1 = t1 / (1.f + __expf(-t1));
            *(unsigned int*)(op + l2 * 2) = pack2(s0, s1);
        }
    }
}

// ---------- ff2 conv (Cin=256 -> 64) + residual -> y ----------
// grid 512 block 128
__global__ __launch_bounds__(128) void ff2_kernel(const unsigned short* __restrict__ hb,
    const float* __restrict__ x2, const float* __restrict__ w,
    const float* __restrict__ bias, float* __restrict__ y)
{
    __shared__ __align__(16) unsigned short in_s[128][136];
    const int bn = blockIdx.x, tid = threadIdx.x;
    const int cog = tid >> 3, c16 = tid & 7, p0 = c16 * 16;
    float acc[4][16];
    #pragma unroll
    for (int a = 0; a < 4; ++a) {
        #pragma unroll
        for (int l = 0; l < 16; ++l) acc[a][l] = 0.f;
    }
    for (int ch = 0; ch < 2; ++ch) {
        __syncthreads();
        in_s[tid][0] = 0; in_s[tid][1] = 0; in_s[tid][130] = 0; in_s[tid][131] = 0;
        for (int idx = tid; idx < 8192; idx += 128) {
            int cl = idx >> 6, lt2 = (idx & 63) * 2;
            *(unsigned int*)&in_s[cl][2 + lt2] =
                *(const unsigned int*)(hb + (size_t)bn * 32768 + (size_t)(ch * 128 + cl) * 128 + lt2);
        }
        __syncthreads();
        for (int cl = 0; cl < 128; ++cl) {
            int cin = ch * 128 + cl;
            float xw[24];
            const uint4* rp = (const uint4*)&in_s[cl][p0];
            #pragma unroll
            for (int k3 = 0; k3 < 3; ++k3) unpack8(rp[k3], &xw[k3 * 8]);
            #pragma unroll
            for (int a = 0; a < 4; ++a) {
                const float* wr = w + ((size_t)(cog * 4 + a) * 256 + cin) * 3;
                float w0 = wr[0], w1 = wr[1], w2 = wr[2];
                #pragma unroll
                for (int l = 0; l < 16; ++l)
                    acc[a][l] = fmaf(w0, xw[l+1], fmaf(w1, xw[l+2], fmaf(w2, xw[l+3], acc[a][l])));
            }
        }
    }
    #pragma unroll
    for (int a = 0; a < 4; ++a) {
        int c = cog * 4 + a;
        float bv = bias[c];
        const float4* xi = (const float4*)(x2 + (size_t)bn * 8192 + c * 128 + p0);
        float4* yo = (float4*)(y + (size_t)bn * 8192 + c * 128 + p0);
        #pragma unroll
        for (int k = 0; k < 4; ++k) {
            float4 xv = xi[k];
            float4 o;
            o.x = acc[a][k*4+0] + bv + xv.x;
            o.y = acc[a][k*4+1] + bv + xv.y;
            o.z = acc[a][k*4+2] + bv + xv.z;
            o.w = acc[a][k*4+3] + bv + xv.w;
            yo[k] = o;
        }
    }
}

// ---------- launch ----------
extern "C" void kernel_launch(void* const* d_in, const int* in_sizes, int n_in,
                              void* d_out, int out_size, void* d_ws, size_t ws_size,
                              hipStream_t stream) {
    (void)in_sizes; (void)n_in; (void)out_size;
    const float* x     = (const float*)d_in[0];
    const float* gn1_g = (const float*)d_in[1];
    const float* gn1_b = (const float*)d_in[2];
    const float* w_qkv = (const float*)d_in[3];
    const float* b_qkv = (const float*)d_in[4];
    const float* w_mg  = (const float*)d_in[5];
    const float* b_mg  = (const float*)d_in[6];
    const float* gn2_g = (const float*)d_in[7];
    const float* gn2_b = (const float*)d_in[8];
    const float* w_f1  = (const float*)d_in[9];
    const float* b_f1  = (const float*)d_in[10];
    const float* w_f2  = (const float*)d_in[11];
    const float* b_f2  = (const float*)d_in[12];
    float* y = (float*)d_out;

    char* ws = (char*)d_ws;
    // fixed small region
    const size_t OFF_SA1 = 0;            // 512*64*4 = 128 KB
    const size_t OFF_SB1 = 131072;
    const size_t OFF_SA2 = 262144;
    const size_t OFF_SB2 = 393216;
    const size_t OFF_NQ  = 524288;       // up to 16*2048*4 = 128 KB
    const size_t OFF_NK  = 655360;
    const size_t OFF_X2  = 1048576;      // 512*64*128*4 = 16.78 MB
    const size_t OFF_CHUNK = 18874368;   // 18 MB
    const size_t H_BYTES = (size_t)512 * 256 * 128 * 2;  // 33.55 MB

    // pick largest CH (b's per chunk) that fits ws_size
    int CH = 1;
    {
        const int cands[5] = {16, 8, 4, 2, 1};
        for (int ci = 0; ci < 5; ++ci) {
            int c = cands[ci];
            size_t qsz   = (size_t)c * 8 * 256 * 1024 * 2;   // c * 4 MB
            size_t asz   = (size_t)c * 8 * 65536 * 2;        // c * 1 MB
            size_t end   = OFF_CHUNK + 4 * qsz + asz;
            size_t hend  = OFF_CHUNK + H_BYTES;
            size_t need  = end > hend ? end : hend;
            if (need <= ws_size) { CH = c; break; }
        }
    }
    const size_t QSZ = (size_t)CH * 8 * 256 * 1024 * 2;
    const size_t ASZ = (size_t)CH * 8 * 65536 * 2;
    const size_t OFF_Q    = OFF_CHUNK;
    const size_t OFF_K    = OFF_Q + QSZ;
    const size_t OFF_V    = OFF_K + QSZ;
    const size_t OFF_ATTN = OFF_V + QSZ;
    const size_t OFF_OUT  = OFF_ATTN + ASZ;

    float* sa1 = (float*)(ws + OFF_SA1);
    float* sb1 = (float*)(ws + OFF_SB1);
    float* sa2 = (float*)(ws + OFF_SA2);
    float* sb2 = (float*)(ws + OFF_SB2);
    float* nqp = (float*)(ws + OFF_NQ);
    float* nkp = (float*)(ws + OFF_NK);
    float* x2  = (float*)(ws + OFF_X2);
    unsigned short* qb   = (unsigned short*)(ws + OFF_Q);
    unsigned short* kb   = (unsigned short*)(ws + OFF_K);
    unsigned short* vbuf = (unsigned short*)(ws + OFF_V);
    unsigned short* attn = (unsigned short*)(ws + OFF_ATTN);
    unsigned short* outp = (unsigned short*)(ws + OFF_OUT);
    unsigned short* hbuf = (unsigned short*)(ws + OFF_CHUNK);  // reuse chunk region

    gnstats_kernel<<<512, 256, 0, stream>>>(x, gn1_g, gn1_b, sa1, sb1);
    const int nch = 16 / CH;
    for (int cidx = 0; cidx < nch; ++cidx) {
        int b0 = cidx * CH;
        conv_qkv_kernel<<<dim3(24, CH * 32), 128, 0, stream>>>(x, sa1, sb1, w_qkv, b_qkv, qb, kb, vbuf, b0);
        norm_kernel<<<dim3(CH * 512, 2), 256, 0, stream>>>(qb, kb, nqp, nkp);
        attnw_kernel<<<dim3(4, 4, CH * 8), 256, 0, stream>>>(qb, kb, nqp, nkp, attn);
        pv_kernel<<<dim3(8, 4, CH * 8), 256, 0, stream>>>(attn, vbuf, outp);
        merge_kernel<<<CH * 32, 128, 0, stream>>>(outp, x, w_mg, b_mg, x2, b0);
    }
    gnstats_kernel<<<512, 256, 0, stream>>>(x2, gn2_g, gn2_b, sa2, sb2);
    ff1_kernel<<<dim3(4, 512), 128, 0, stream>>>(x2, sa2, sb2, w_f1, b_f1, hbuf);
    ff2_kernel<<<512, 128, 0, stream>>>(hbuf, x2, w_f2, b_f2, y);
}

// Round 3
// 782.128 us; speedup vs baseline: 2.7012x; 2.7012x over previous
//
#include <hip/hip_runtime.h>
#include <hip/hip_bf16.h>

#define DEV __device__ __forceinline__

typedef __attribute__((ext_vector_type(8))) __bf16 bf16x8;
typedef __attribute__((ext_vector_type(4))) float f32x4;

// ---------- bf16 helpers (bit-level) ----------
DEV float bfu_lo(unsigned int u) { return __uint_as_float(u << 16); }
DEV float bfu_hi(unsigned int u) { return __uint_as_float(u & 0xffff0000u); }
DEV unsigned short f2bf(float f) {
    union { float f; unsigned int u; } cv; cv.f = f;
    unsigned int u = cv.u;
    unsigned int r = (u + 0x7fffu + ((u >> 16) & 1u)) >> 16;  // RNE
    return (unsigned short)r;
}
DEV unsigned int pack2(float a, float b) {
    return (unsigned int)f2bf(a) | ((unsigned int)f2bf(b) << 16);
}
DEV void unpack8(uint4 u, float* f) {
    f[0] = bfu_lo(u.x); f[1] = bfu_hi(u.x);
    f[2] = bfu_lo(u.y); f[3] = bfu_hi(u.y);
    f[4] = bfu_lo(u.z); f[5] = bfu_hi(u.z);
    f[6] = bfu_lo(u.w); f[7] = bfu_hi(u.w);
}

// dims: B=16 N=32 D=64 H=8 S=8 LT=128 DE=256 L=16
// BN=512 BH=128 NS=256 DL=1024 DQKV=1536

// ---------- GroupNorm stats ----------
__global__ __launch_bounds__(256) void gnstats_kernel(const float* __restrict__ src,
    const float* __restrict__ gamma, const float* __restrict__ beta,
    float* __restrict__ sa, float* __restrict__ sb)
{
    __shared__ float gsum[8], gsq[8];
    const int s = blockIdx.x, tid = threadIdx.x;
    const int g = tid >> 5, il = tid & 31;
    const float* p = src + (size_t)s * 8192 + g * 1024 + il;
    float sm = 0.f, sq = 0.f;
    #pragma unroll
    for (int m = 0; m < 32; ++m) {
        float v = p[m * 32];
        sm += v; sq += v * v;
    }
    #pragma unroll
    for (int m = 16; m; m >>= 1) { sm += __shfl_xor(sm, m); sq += __shfl_xor(sq, m); }
    if (il == 0) { gsum[g] = sm; gsq[g] = sq; }
    __syncthreads();
    if (tid < 64) {
        int gg = tid >> 3;
        float mu = gsum[gg] * (1.f / 1024.f);
        float var = gsq[gg] * (1.f / 1024.f) - mu * mu;
        float a = gamma[tid] * rsqrtf(var + 1e-5f);
        sa[s * 64 + tid] = a;
        sb[s * 64 + tid] = beta[tid] - mu * a;
    }
}

// ---------- weight prep: w_qkv (1536,64,3) f32 -> wq[k][1536][64] bf16 ----------
__global__ __launch_bounds__(256) void prep_wq_kernel(const float* __restrict__ w,
    unsigned short* __restrict__ dst)
{
    int i = blockIdx.x * 256 + threadIdx.x;   // over 1536*64
    if (i < 98304) {
        #pragma unroll
        for (int k = 0; k < 3; ++k)
            dst[k * 98304 + i] = f2bf(w[(size_t)i * 3 + k]);
    }
}

// ---------- QKV conv via MFMA: per block one scene x 128 couts ----------
// grid (12, CH*32), block 256 (4 waves)
__global__ __launch_bounds__(256) void conv_qkv_mfma(const float* __restrict__ x,
    const float* __restrict__ sa, const float* __restrict__ sb,
    const unsigned short* __restrict__ wq, const float* __restrict__ bias,
    unsigned short* __restrict__ qb, unsigned short* __restrict__ kb,
    unsigned short* __restrict__ vb, int b0)
{
    __shared__ __align__(16) char smem[74048];
    unsigned short (*xt)[72]  = (unsigned short(*)[72])smem;             // [130][72]
    unsigned short (*ws_)[128][72] = (unsigned short(*)[128][72])(smem + 18720); // [3][128][72]
    unsigned short (*ct)[136] = (unsigned short(*)[136])smem;            // [128][136] overlay

    const int mc = blockIdx.x, sl = blockIdx.y, tid = threadIdx.x;
    const int bn = b0 * 32 + sl;
    // stage x^T (GN applied) : rows = 1+lt, cols = cin
    for (int idx = tid; idx < 8192; idx += 256) {
        int lt = idx & 127, c = idx >> 7;
        float v = x[(size_t)bn * 8192 + c * 128 + lt] * sa[bn * 64 + c] + sb[bn * 64 + c];
        xt[1 + lt][c] = f2bf(v);
    }
    if (tid < 64) { xt[0][tid] = 0; xt[129][tid] = 0; }
    // stage weights for this cout chunk: [3][128][64]
    for (int idx = tid; idx < 3072; idx += 256) {
        int k = idx >> 10, rem = idx & 1023, co = rem >> 3, ci8 = (rem & 7) * 8;
        *(uint4*)&ws_[k][co][ci8] =
            *(const uint4*)(wq + (size_t)k * 98304 + (size_t)(mc * 128 + co) * 64 + ci8);
    }
    __syncthreads();
    const int w = tid >> 6, lane = tid & 63;
    const int lrow = lane & 15, lko = (lane >> 4) * 8;
    f32x4 acc[2][8];
    #pragma unroll
    for (int m = 0; m < 2; ++m)
        #pragma unroll
        for (int n = 0; n < 8; ++n) acc[m][n] = (f32x4)0.f;
    #pragma unroll
    for (int k = 0; k < 3; ++k) {
        #pragma unroll
        for (int kc = 0; kc < 2; ++kc) {
            bf16x8 a0 = *(const bf16x8*)&ws_[k][w * 32 + lrow][kc * 32 + lko];
            bf16x8 a1 = *(const bf16x8*)&ws_[k][w * 32 + 16 + lrow][kc * 32 + lko];
            #pragma unroll
            for (int n = 0; n < 8; ++n) {
                bf16x8 b = *(const bf16x8*)&xt[n * 16 + lrow + k][kc * 32 + lko];
                acc[0][n] = __builtin_amdgcn_mfma_f32_16x16x32_bf16(a0, b, acc[0][n], 0, 0, 0);
                acc[1][n] = __builtin_amdgcn_mfma_f32_16x16x32_bf16(a1, b, acc[1][n], 0, 0, 0);
            }
        }
    }
    __syncthreads();
    // C -> LDS (rows = cout_local 0..127, cols = lt 0..127)
    const int c0 = mc * 128;
    float bv[2][4];
    #pragma unroll
    for (int m = 0; m < 2; ++m)
        #pragma unroll
        for (int r = 0; r < 4; ++r)
            bv[m][r] = bias[c0 + w * 32 + m * 16 + (lane >> 4) * 4 + r];
    #pragma unroll
    for (int m = 0; m < 2; ++m)
        #pragma unroll
        for (int n = 0; n < 8; ++n)
            #pragma unroll
            for (int r = 0; r < 4; ++r)
                ct[w * 32 + m * 16 + (lane >> 4) * 4 + r][n * 16 + lrow] =
                    f2bf(acc[m][n][r] + bv[m][r]);
    __syncthreads();
    const int t = mc >> 2, h_base = (mc & 3) * 2;
    const int bl = sl >> 5, n_tr = sl & 31;
    if (t < 2) {
        unsigned short* dst = t ? kb : qb;
        for (int idx = tid; idx < 2048; idx += 256) {
            int lb = idx & 1;
            int d  = (idx >> 1) & 63;
            int s  = (idx >> 7) & 7;
            int hl = idx >> 10;
            unsigned int uu[4];
            #pragma unroll
            for (int e2 = 0; e2 < 4; ++e2) {
                unsigned short w0 = ct[hl * 64 + d][(lb * 8 + e2 * 2) * 8 + s];
                unsigned short w1 = ct[hl * 64 + d][(lb * 8 + e2 * 2 + 1) * 8 + s];
                uu[e2] = (unsigned int)w0 | ((unsigned int)w1 << 16);
            }
            uint4 o = {uu[0], uu[1], uu[2], uu[3]};
            size_t a = ((size_t)((bl * 8 + h_base + hl) * 256 + n_tr * 8 + s)) * 1024 + d * 16 + lb * 8;
            *(uint4*)(dst + a) = o;
        }
    } else {
        // V stored feature-major: [bh][dl][ns]
        for (int idx = tid; idx < 2048; idx += 256) {
            int l = idx & 15, d = (idx >> 4) & 63, hl = idx >> 10;
            uint4 o = *(const uint4*)&ct[hl * 64 + d][l * 8];
            size_t a = ((size_t)((bl * 8 + h_base + hl) * 1024 + d * 16 + l)) * 256 + n_tr * 8;
            *(uint4*)(vb + a) = o;
        }
    }
}

// ---------- token norms |q|^2, |k|^2 ----------
__global__ __launch_bounds__(256) void norm_kernel(const unsigned short* __restrict__ qb,
    const unsigned short* __restrict__ kb, float* __restrict__ nq, float* __restrict__ nk)
{
    const int tok = blockIdx.x * 4 + (threadIdx.x >> 6);
    const int lane = threadIdx.x & 63;
    const unsigned short* src = blockIdx.y ? kb : qb;
    float* dst = blockIdx.y ? nk : nq;
    const uint4* p = (const uint4*)(src + (size_t)tok * 1024 + lane * 16);
    float s = 0.f;
    #pragma unroll
    for (int r = 0; r < 2; ++r) {
        float f[8]; unpack8(p[r], f);
        #pragma unroll
        for (int e = 0; e < 8; ++e) s = fmaf(f[e], f[e], s);
    }
    #pragma unroll
    for (int m = 32; m; m >>= 1) s += __shfl_xor(s, m);
    if (lane == 0) dst[tok] = s;
}

// ---------- attn weights via MFMA: S=QK^T, W=rsqrt(nq+nk-2S) ----------
// grid (2,2,CH*8), block 256 (4 waves, 2x2 wave tiles of 64x64)
__global__ __launch_bounds__(256) void attnw_mfma(const unsigned short* __restrict__ qb,
    const unsigned short* __restrict__ kb, const float* __restrict__ nq,
    const float* __restrict__ nk, unsigned short* __restrict__ attn)
{
    __shared__ __align__(16) unsigned short q_s[128][136];
    __shared__ __align__(16) unsigned short k_s[128][136];
    const int bh = blockIdx.z, i0 = blockIdx.y * 128, j0 = blockIdx.x * 128;
    const int tid = threadIdx.x, w = tid >> 6, lane = tid & 63;
    const int wi = w >> 1, wj = w & 1;
    const int lrow = lane & 15, lko = (lane >> 4) * 8;
    f32x4 acc[4][4];
    #pragma unroll
    for (int m = 0; m < 4; ++m)
        #pragma unroll
        for (int n = 0; n < 4; ++n) acc[m][n] = (f32x4)0.f;
    const size_t tb = (size_t)bh * 262144;
    for (int fc = 0; fc < 8; ++fc) {
        __syncthreads();
        for (int idx = tid; idx < 2048; idx += 256) {
            int r = idx >> 4, c8 = (idx & 15) * 8;
            *(uint4*)&q_s[r][c8] = *(const uint4*)(qb + tb + (size_t)(i0 + r) * 1024 + fc * 128 + c8);
            *(uint4*)&k_s[r][c8] = *(const uint4*)(kb + tb + (size_t)(j0 + r) * 1024 + fc * 128 + c8);
        }
        __syncthreads();
        #pragma unroll
        for (int ks = 0; ks < 4; ++ks) {
            bf16x8 a[4], b[4];
            #pragma unroll
            for (int m = 0; m < 4; ++m) a[m] = *(const bf16x8*)&q_s[wi * 64 + m * 16 + lrow][ks * 32 + lko];
            #pragma unroll
            for (int n = 0; n < 4; ++n) b[n] = *(const bf16x8*)&k_s[wj * 64 + n * 16 + lrow][ks * 32 + lko];
            #pragma unroll
            for (int m = 0; m < 4; ++m)
                #pragma unroll
                for (int n = 0; n < 4; ++n)
                    acc[m][n] = __builtin_amdgcn_mfma_f32_16x16x32_bf16(a[m], b[n], acc[m][n], 0, 0, 0);
        }
    }
    float nqv[4][4], nkv[4];
    #pragma unroll
    for (int m = 0; m < 4; ++m)
        #pragma unroll
        for (int r = 0; r < 4; ++r)
            nqv[m][r] = nq[bh * 256 + i0 + wi * 64 + m * 16 + (lane >> 4) * 4 + r];
    #pragma unroll
    for (int n = 0; n < 4; ++n)
        nkv[n] = nk[bh * 256 + j0 + wj * 64 + n * 16 + lrow];
    __syncthreads();
    #pragma unroll
    for (int m = 0; m < 4; ++m)
        #pragma unroll
        for (int n = 0; n < 4; ++n)
            #pragma unroll
            for (int r = 0; r < 4; ++r) {
                float sq = nqv[m][r] + nkv[n] - 2.f * acc[m][n][r];
                q_s[wi * 64 + m * 16 + (lane >> 4) * 4 + r][wj * 64 + n * 16 + lrow] =
                    f2bf(rsqrtf(fmaxf(sq, 1e-12f)));
            }
    __syncthreads();
    for (int idx = tid; idx < 2048; idx += 256) {
        int r = idx >> 4, c8 = (idx & 15) * 8;
        *(uint4*)(attn + (size_t)bh * 65536 + (size_t)(i0 + r) * 256 + j0 + c8) =
            *(const uint4*)&q_s[r][c8];
    }
}

// ---------- out = attn @ V via MFMA (V feature-major: C[i][f] = sum_j A[i][j] V^T[f][j]) ----------
// grid (8,2,CH*8), block 256
__global__ __launch_bounds__(256) void pv_mfma(const unsigned short* __restrict__ attn,
    const unsigned short* __restrict__ vb, unsigned short* __restrict__ outb)
{
    __shared__ __align__(16) unsigned short a_s[128][136];
    __shared__ __align__(16) unsigned short b_s[128][136];
    const int bh = blockIdx.z, i0 = blockIdx.y * 128, f0 = blockIdx.x * 128;
    const int tid = threadIdx.x, w = tid >> 6, lane = tid & 63;
    const int wi = w >> 1, wf = w & 1;
    const int lrow = lane & 15, lko = (lane >> 4) * 8;
    f32x4 acc[4][4];
    #pragma unroll
    for (int m = 0; m < 4; ++m)
        #pragma unroll
        for (int n = 0; n < 4; ++n) acc[m][n] = (f32x4)0.f;
    for (int jc = 0; jc < 2; ++jc) {
        __syncthreads();
        for (int idx = tid; idx < 2048; idx += 256) {
            int r = idx >> 4, c8 = (idx & 15) * 8;
            *(uint4*)&a_s[r][c8] = *(const uint4*)(attn + (size_t)bh * 65536 + (size_t)(i0 + r) * 256 + jc * 128 + c8);
            *(uint4*)&b_s[r][c8] = *(const uint4*)(vb + (size_t)bh * 262144 + (size_t)(f0 + r) * 256 + jc * 128 + c8);
        }
        __syncthreads();
        #pragma unroll
        for (int ks = 0; ks < 4; ++ks) {
            bf16x8 a[4], b[4];
            #pragma unroll
            for (int m = 0; m < 4; ++m) a[m] = *(const bf16x8*)&a_s[wi * 64 + m * 16 + lrow][ks * 32 + lko];
            #pragma unroll
            for (int n = 0; n < 4; ++n) b[n] = *(const bf16x8*)&b_s[wf * 64 + n * 16 + lrow][ks * 32 + lko];
            #pragma unroll
            for (int m = 0; m < 4; ++m)
                #pragma unroll
                for (int n = 0; n < 4; ++n)
                    acc[m][n] = __builtin_amdgcn_mfma_f32_16x16x32_bf16(a[m], b[n], acc[m][n], 0, 0, 0);
        }
    }
    __syncthreads();
    #pragma unroll
    for (int m = 0; m < 4; ++m)
        #pragma unroll
        for (int n = 0; n < 4; ++n)
            #pragma unroll
            for (int r = 0; r < 4; ++r)
                a_s[wi * 64 + m * 16 + (lane >> 4) * 4 + r][wf * 64 + n * 16 + lrow] = f2bf(acc[m][n][r]);
    __syncthreads();
    for (int idx = tid; idx < 2048; idx += 256) {
        int r = idx >> 4, c8 = (idx & 15) * 8;
        *(uint4*)(outb + (size_t)bh * 262144 + (size_t)(i0 + r) * 1024 + f0 + c8) =
            *(const uint4*)&a_s[r][c8];
    }
}

// ---------- merge conv (Cin=512,K=3) + residual -> x2 ----------
// grid CH*32 block 256; thread = 2 couts x 16 lt
__global__ __launch_bounds__(256) void merge_kernel(const unsigned short* __restrict__ outb,
    const float* __restrict__ x, const float* __restrict__ w,
    const float* __restrict__ bias, float* __restrict__ x2, int b0)
{
    __shared__ __align__(16) unsigned short in_s[128][136];
    const int sl = blockIdx.x, tid = threadIdx.x;
    const int bn = b0 * 32 + sl;
    const int bl = sl >> 5, n = sl & 31;
    const int cog = tid >> 3, c16 = tid & 7, p0 = c16 * 16;
    float acc[2][16];
    #pragma unroll
    for (int a = 0; a < 2; ++a)
        #pragma unroll
        for (int l = 0; l < 16; ++l) acc[a][l] = 0.f;
    for (int ch = 0; ch < 4; ++ch) {
        __syncthreads();
        if (tid < 128) { in_s[tid][0] = 0; in_s[tid][1] = 0; in_s[tid][130] = 0; in_s[tid][131] = 0; }
        for (int idx = tid; idx < 16384; idx += 256) {
            int hh = idx >> 13, rem = idx & 8191;
            int st = rem >> 10, feat = rem & 1023;
            int d = feat >> 4, l = feat & 15;
            in_s[hh * 64 + d][2 + l * 8 + st] =
                outb[((size_t)((bl * 8 + ch * 2 + hh) * 256 + n * 8 + st)) * 1024 + feat];
        }
        __syncthreads();
        for (int cl = 0; cl < 128; ++cl) {
            int cin = ch * 128 + cl;
            float xw[24];
            const uint4* rp = (const uint4*)&in_s[cl][p0];
            #pragma unroll
            for (int k3 = 0; k3 < 3; ++k3) unpack8(rp[k3], &xw[k3 * 8]);
            #pragma unroll
            for (int a = 0; a < 2; ++a) {
                const float* wr = w + ((size_t)(cog * 2 + a) * 512 + cin) * 3;
                float w0 = wr[0], w1 = wr[1], w2 = wr[2];
                #pragma unroll
                for (int l = 0; l < 16; ++l)
                    acc[a][l] = fmaf(w0, xw[l+1], fmaf(w1, xw[l+2], fmaf(w2, xw[l+3], acc[a][l])));
            }
        }
    }
    #pragma unroll
    for (int a = 0; a < 2; ++a) {
        int c = cog * 2 + a;
        float bv = bias[c];
        const float4* xi = (const float4*)(x + (size_t)bn * 8192 + c * 128 + p0);
        float4* xo = (float4*)(x2 + (size_t)bn * 8192 + c * 128 + p0);
        #pragma unroll
        for (int k = 0; k < 4; ++k) {
            float4 xv = xi[k];
            float4 o;
            o.x = acc[a][k*4+0] + bv + xv.x;
            o.y = acc[a][k*4+1] + bv + xv.y;
            o.z = acc[a][k*4+2] + bv + xv.z;
            o.w = acc[a][k*4+3] + bv + xv.w;
            xo[k] = o;
        }
    }
}

// ---------- ff1 conv (Cin=64 -> 256) with GN2 on the fly + swish -> h bf16 ----------
// grid (4, 512) block 128
__global__ __launch_bounds__(128) void ff1_kernel(const float* __restrict__ x2,
    const float* __restrict__ sa, const float* __restrict__ sb,
    const float* __restrict__ w, const float* __restrict__ bias,
    unsigned short* __restrict__ hb)
{
    __shared__ __align__(16) float sxp[64][132];
    const int chunk = blockIdx.x, bn = blockIdx.y, tid = threadIdx.x;
    for (int idx = tid; idx < 64 * 132; idx += 128) {
        int r = idx / 132, c = idx - r * 132;
        float v = 0.f;
        if (c >= 1 && c <= 128)
            v = x2[(size_t)bn * 8192 + r * 128 + (c - 1)] * sa[bn * 64 + r] + sb[bn * 64 + r];
        sxp[r][c] = v;
    }
    __syncthreads();
    const int cog = tid >> 3, c16 = tid & 7, p0 = c16 * 16;
    const int c0 = chunk * 64 + cog * 4;
    float acc[4][16];
    #pragma unroll
    for (int a = 0; a < 4; ++a)
        #pragma unroll
        for (int l = 0; l < 16; ++l) acc[a][l] = 0.f;
    for (int cin = 0; cin < 64; ++cin) {
        float xw[20];
        const float4* row4 = (const float4*)&sxp[cin][p0];
        #pragma unroll
        for (int k = 0; k < 5; ++k) {
            float4 t = row4[k];
            xw[k*4+0] = t.x; xw[k*4+1] = t.y; xw[k*4+2] = t.z; xw[k*4+3] = t.w;
        }
        #pragma unroll
        for (int a = 0; a < 4; ++a) {
            const float* wr = w + ((size_t)(c0 + a) * 64 + cin) * 3;
            float w0 = wr[0], w1 = wr[1], w2 = wr[2];
            #pragma unroll
            for (int l = 0; l < 16; ++l)
                acc[a][l] = fmaf(w0, xw[l], fmaf(w1, xw[l+1], fmaf(w2, xw[l+2], acc[a][l])));
        }
    }
    #pragma unroll
    for (int a = 0; a < 4; ++a) {
        int c = c0 + a;
        float bv = bias[c];
        unsigned short* op = hb + (size_t)bn * 32768 + (size_t)c * 128 + p0;
        #pragma unroll
        for (int l2 = 0; l2 < 8; ++l2) {
            float t0 = acc[a][l2*2]   + bv; float s0 = t0 / (1.f + __expf(-t0));
            float t1 = acc[a][l2*2+1] + bv; float s1 = t1 / (1.f + __expf(-t1));
            *(unsigned int*)(op + l2 * 2) = pack2(s0, s1);
        }
    }
}

// ---------- ff2 conv (Cin=256 -> 64) + residual -> y ----------
// grid 512 block 256; thread = 2 couts x 16 lt
__global__ __launch_bounds__(256) void ff2_kernel(const unsigned short* __restrict__ hb,
    const float* __restrict__ x2, const float* __restrict__ w,
    const float* __restrict__ bias, float* __restrict__ y)
{
    __shared__ __align__(16) unsigned short in_s[128][136];
    const int bn = blockIdx.x, tid = threadIdx.x;
    const int cog = tid >> 3, c16 = tid & 7, p0 = c16 * 16;
    float acc[2][16];
    #pragma unroll
    for (int a = 0; a < 2; ++a)
        #pragma unroll
        for (int l = 0; l < 16; ++l) acc[a][l] = 0.f;
    for (int ch = 0; ch < 2; ++ch) {
        __syncthreads();
        if (tid < 128) { in_s[tid][0] = 0; in_s[tid][1] = 0; in_s[tid][130] = 0; in_s[tid][131] = 0; }
        for (int idx = tid; idx < 8192; idx += 256) {
            int cl = idx >> 6, lt2 = (idx & 63) * 2;
            *(unsigned int*)&in_s[cl][2 + lt2] =
                *(const unsigned int*)(hb + (size_t)bn * 32768 + (size_t)(ch * 128 + cl) * 128 + lt2);
        }
        __syncthreads();
        for (int cl = 0; cl < 128; ++cl) {
            int cin = ch * 128 + cl;
            float xw[24];
            const uint4* rp = (const uint4*)&in_s[cl][p0];
            #pragma unroll
            for (int k3 = 0; k3 < 3; ++k3) unpack8(rp[k3], &xw[k3 * 8]);
            #pragma unroll
            for (int a = 0; a < 2; ++a) {
                const float* wr = w + ((size_t)(cog * 2 + a) * 256 + cin) * 3;
                float w0 = wr[0], w1 = wr[1], w2 = wr[2];
                #pragma unroll
                for (int l = 0; l < 16; ++l)
                    acc[a][l] = fmaf(w0, xw[l+1], fmaf(w1, xw[l+2], fmaf(w2, xw[l+3], acc[a][l])));
            }
        }
    }
    #pragma unroll
    for (int a = 0; a < 2; ++a) {
        int c = cog * 2 + a;
        float bv = bias[c];
        const float4* xi = (const float4*)(x2 + (size_t)bn * 8192 + c * 128 + p0);
        float4* yo = (float4*)(y + (size_t)bn * 8192 + c * 128 + p0);
        #pragma unroll
        for (int k = 0; k < 4; ++k) {
            float4 xv = xi[k];
            float4 o;
            o.x = acc[a][k*4+0] + bv + xv.x;
            o.y = acc[a][k*4+1] + bv + xv.y;
            o.z = acc[a][k*4+2] + bv + xv.z;
            o.w = acc[a][k*4+3] + bv + xv.w;
            yo[k] = o;
        }
    }
}

// ---------- launch ----------
extern "C" void kernel_launch(void* const* d_in, const int* in_sizes, int n_in,
                              void* d_out, int out_size, void* d_ws, size_t ws_size,
                              hipStream_t stream) {
    (void)in_sizes; (void)n_in; (void)out_size;
    const float* x     = (const float*)d_in[0];
    const float* gn1_g = (const float*)d_in[1];
    const float* gn1_b = (const float*)d_in[2];
    const float* w_qkv = (const float*)d_in[3];
    const float* b_qkv = (const float*)d_in[4];
    const float* w_mg  = (const float*)d_in[5];
    const float* b_mg  = (const float*)d_in[6];
    const float* gn2_g = (const float*)d_in[7];
    const float* gn2_b = (const float*)d_in[8];
    const float* w_f1  = (const float*)d_in[9];
    const float* b_f1  = (const float*)d_in[10];
    const float* w_f2  = (const float*)d_in[11];
    const float* b_f2  = (const float*)d_in[12];
    float* y = (float*)d_out;

    char* ws = (char*)d_ws;
    const size_t OFF_SA1 = 0;
    const size_t OFF_SB1 = 131072;
    const size_t OFF_SA2 = 262144;
    const size_t OFF_SB2 = 393216;
    const size_t OFF_NQ  = 524288;
    const size_t OFF_NK  = 655360;
    const size_t OFF_WQ  = 786432;        // 589824 B
    const size_t OFF_X2  = 2097152;       // 16.78 MB
    const size_t OFF_CHUNK = 20971520;    // 20 MB
    const size_t H_BYTES = 33554432;      // h buffer 33.55 MB

    // pick largest CH that fits: need = OFF_CHUNK + max(3*qsz + asz, H_BYTES)
    int CH = 1;
    {
        const int cands[5] = {16, 8, 4, 2, 1};
        for (int ci = 0; ci < 5; ++ci) {
            int c = cands[ci];
            size_t qsz = (size_t)c * 4194304;
            size_t asz = (size_t)c * 1048576;
            size_t body = 3 * qsz + asz;
            if (body < H_BYTES) body = H_BYTES;
            if (OFF_CHUNK + body <= ws_size) { CH = c; break; }
        }
    }
    const size_t QSZ = (size_t)CH * 4194304;
    const size_t OFF_Q    = OFF_CHUNK;
    const size_t OFF_K    = OFF_Q + QSZ;
    const size_t OFF_V    = OFF_K + QSZ;
    const size_t OFF_ATTN = OFF_V + QSZ;

    float* sa1 = (float*)(ws + OFF_SA1);
    float* sb1 = (float*)(ws + OFF_SB1);
    float* sa2 = (float*)(ws + OFF_SA2);
    float* sb2 = (float*)(ws + OFF_SB2);
    float* nqp = (float*)(ws + OFF_NQ);
    float* nkp = (float*)(ws + OFF_NK);
    unsigned short* wqb = (unsigned short*)(ws + OFF_WQ);
    float* x2  = (float*)(ws + OFF_X2);
    unsigned short* qb   = (unsigned short*)(ws + OFF_Q);
    unsigned short* kb   = (unsigned short*)(ws + OFF_K);
    unsigned short* vbuf = (unsigned short*)(ws + OFF_V);
    unsigned short* attn = (unsigned short*)(ws + OFF_ATTN);
    unsigned short* outp = (unsigned short*)(ws + OFF_Q);      // reuse q (dead after attnw)
    unsigned short* hbuf = (unsigned short*)(ws + OFF_CHUNK);  // reuse chunk region

    gnstats_kernel<<<512, 256, 0, stream>>>(x, gn1_g, gn1_b, sa1, sb1);
    prep_wq_kernel<<<384, 256, 0, stream>>>(w_qkv, wqb);
    const int nch = 16 / CH;
    for (int cidx = 0; cidx < nch; ++cidx) {
        int b0 = cidx * CH;
        conv_qkv_mfma<<<dim3(12, CH * 32), 256, 0, stream>>>(x, sa1, sb1, wqb, b_qkv, qb, kb, vbuf, b0);
        norm_kernel<<<dim3(CH * 512, 2), 256, 0, stream>>>(qb, kb, nqp, nkp);
        attnw_mfma<<<dim3(2, 2, CH * 8), 256, 0, stream>>>(qb, kb, nqp, nkp, attn);
        pv_mfma<<<dim3(8, 2, CH * 8), 256, 0, stream>>>(attn, vbuf, outp);
        merge_kernel<<<CH * 32, 256, 0, stream>>>(outp, x, w_mg, b_mg, x2, b0);
    }
    gnstats_kernel<<<512, 256, 0, stream>>>(x2, gn2_g, gn2_b, sa2, sb2);
    ff1_kernel<<<dim3(4, 512), 128, 0, stream>>>(x2, sa2, sb2, w_f1, b_f1, hbuf);
    ff2_kernel<<<512, 256, 0, stream>>>(hbuf, x2, w_f2, b_f2, y);
}

// Round 4
// 431.162 us; speedup vs baseline: 4.8999x; 1.8140x over previous
//
#include <hip/hip_runtime.h>
#include <hip/hip_bf16.h>

#define DEV __device__ __forceinline__

typedef __attribute__((ext_vector_type(8))) __bf16 bf16x8;
typedef __attribute__((ext_vector_type(4))) float f32x4;

// ---------- bf16 helpers (bit-level) ----------
DEV float bfu_lo(unsigned int u) { return __uint_as_float(u << 16); }
DEV float bfu_hi(unsigned int u) { return __uint_as_float(u & 0xffff0000u); }
DEV unsigned short f2bf(float f) {
    union { float f; unsigned int u; } cv; cv.f = f;
    unsigned int u = cv.u;
    unsigned int r = (u + 0x7fffu + ((u >> 16) & 1u)) >> 16;  // RNE
    return (unsigned short)r;
}
DEV unsigned int pack2(float a, float b) {
    return (unsigned int)f2bf(a) | ((unsigned int)f2bf(b) << 16);
}
DEV void unpack8(uint4 u, float* f) {
    f[0] = bfu_lo(u.x); f[1] = bfu_hi(u.x);
    f[2] = bfu_lo(u.y); f[3] = bfu_hi(u.y);
    f[4] = bfu_lo(u.z); f[5] = bfu_hi(u.z);
    f[6] = bfu_lo(u.w); f[7] = bfu_hi(u.w);
}

// dims: B=16 N=32 D=64 H=8 S=8 LT=128 DE=256 L=16
// BN=512 BH=128 NS=256 DL=1024 DQKV=1536

// ---------- GroupNorm stats ----------
__global__ __launch_bounds__(256) void gnstats_kernel(const float* __restrict__ src,
    const float* __restrict__ gamma, const float* __restrict__ beta,
    float* __restrict__ sa, float* __restrict__ sb)
{
    __shared__ float gsum[8], gsq[8];
    const int s = blockIdx.x, tid = threadIdx.x;
    const int g = tid >> 5, il = tid & 31;
    const float* p = src + (size_t)s * 8192 + g * 1024 + il;
    float sm = 0.f, sq = 0.f;
    #pragma unroll
    for (int m = 0; m < 32; ++m) {
        float v = p[m * 32];
        sm += v; sq += v * v;
    }
    #pragma unroll
    for (int m = 16; m; m >>= 1) { sm += __shfl_xor(sm, m); sq += __shfl_xor(sq, m); }
    if (il == 0) { gsum[g] = sm; gsq[g] = sq; }
    __syncthreads();
    if (tid < 64) {
        int gg = tid >> 3;
        float mu = gsum[gg] * (1.f / 1024.f);
        float var = gsq[gg] * (1.f / 1024.f) - mu * mu;
        float a = gamma[tid] * rsqrtf(var + 1e-5f);
        sa[s * 64 + tid] = a;
        sb[s * 64 + tid] = beta[tid] - mu * a;
    }
}

// ---------- generic weight prep: src[i][k] (k=0..2 innermost) -> dst[k][i] bf16 ----------
__global__ __launch_bounds__(256) void prep_w_kernel(const float* __restrict__ w,
    unsigned short* __restrict__ dst, int n)
{
    int i = blockIdx.x * 256 + threadIdx.x;
    if (i < n) {
        #pragma unroll
        for (int k = 0; k < 3; ++k)
            dst[k * n + i] = f2bf(w[(size_t)i * 3 + k]);
    }
}

// ---------- QKV conv via MFMA: per block one scene x 128 couts ----------
// grid (12, CH*32), block 256 (4 waves)
__global__ __launch_bounds__(256) void conv_qkv_mfma(const float* __restrict__ x,
    const float* __restrict__ sa, const float* __restrict__ sb,
    const unsigned short* __restrict__ wq, const float* __restrict__ bias,
    unsigned short* __restrict__ qb, unsigned short* __restrict__ kb,
    unsigned short* __restrict__ vb, int b0)
{
    __shared__ __align__(16) char smem[74048];
    unsigned short (*xt)[72]  = (unsigned short(*)[72])smem;             // [130][72]
    unsigned short (*ws_)[128][72] = (unsigned short(*)[128][72])(smem + 18720); // [3][128][72]
    unsigned short (*ct)[136] = (unsigned short(*)[136])smem;            // [128][136] overlay

    const int mc = blockIdx.x, sl = blockIdx.y, tid = threadIdx.x;
    const int bn = b0 * 32 + sl;
    for (int idx = tid; idx < 8192; idx += 256) {
        int lt = idx & 127, c = idx >> 7;
        float v = x[(size_t)bn * 8192 + c * 128 + lt] * sa[bn * 64 + c] + sb[bn * 64 + c];
        xt[1 + lt][c] = f2bf(v);
    }
    if (tid < 64) { xt[0][tid] = 0; xt[129][tid] = 0; }
    for (int idx = tid; idx < 3072; idx += 256) {
        int k = idx >> 10, rem = idx & 1023, co = rem >> 3, ci8 = (rem & 7) * 8;
        *(uint4*)&ws_[k][co][ci8] =
            *(const uint4*)(wq + (size_t)k * 98304 + (size_t)(mc * 128 + co) * 64 + ci8);
    }
    __syncthreads();
    const int w = tid >> 6, lane = tid & 63;
    const int lrow = lane & 15, lko = (lane >> 4) * 8;
    f32x4 acc[2][8];
    #pragma unroll
    for (int m = 0; m < 2; ++m)
        #pragma unroll
        for (int n = 0; n < 8; ++n) acc[m][n] = (f32x4)0.f;
    #pragma unroll
    for (int k = 0; k < 3; ++k) {
        #pragma unroll
        for (int kc = 0; kc < 2; ++kc) {
            bf16x8 a0 = *(const bf16x8*)&ws_[k][w * 32 + lrow][kc * 32 + lko];
            bf16x8 a1 = *(const bf16x8*)&ws_[k][w * 32 + 16 + lrow][kc * 32 + lko];
            #pragma unroll
            for (int n = 0; n < 8; ++n) {
                bf16x8 b = *(const bf16x8*)&xt[n * 16 + lrow + k][kc * 32 + lko];
                acc[0][n] = __builtin_amdgcn_mfma_f32_16x16x32_bf16(a0, b, acc[0][n], 0, 0, 0);
                acc[1][n] = __builtin_amdgcn_mfma_f32_16x16x32_bf16(a1, b, acc[1][n], 0, 0, 0);
            }
        }
    }
    __syncthreads();
    const int c0 = mc * 128;
    float bv[2][4];
    #pragma unroll
    for (int m = 0; m < 2; ++m)
        #pragma unroll
        for (int r = 0; r < 4; ++r)
            bv[m][r] = bias[c0 + w * 32 + m * 16 + (lane >> 4) * 4 + r];
    #pragma unroll
    for (int m = 0; m < 2; ++m)
        #pragma unroll
        for (int n = 0; n < 8; ++n)
            #pragma unroll
            for (int r = 0; r < 4; ++r)
                ct[w * 32 + m * 16 + (lane >> 4) * 4 + r][n * 16 + lrow] =
                    f2bf(acc[m][n][r] + bv[m][r]);
    __syncthreads();
    const int t = mc >> 2, h_base = (mc & 3) * 2;
    const int bl = sl >> 5, n_tr = sl & 31;
    if (t < 2) {
        unsigned short* dst = t ? kb : qb;
        for (int idx = tid; idx < 2048; idx += 256) {
            int lb = idx & 1;
            int d  = (idx >> 1) & 63;
            int s  = (idx >> 7) & 7;
            int hl = idx >> 10;
            unsigned int uu[4];
            #pragma unroll
            for (int e2 = 0; e2 < 4; ++e2) {
                unsigned short w0 = ct[hl * 64 + d][(lb * 8 + e2 * 2) * 8 + s];
                unsigned short w1 = ct[hl * 64 + d][(lb * 8 + e2 * 2 + 1) * 8 + s];
                uu[e2] = (unsigned int)w0 | ((unsigned int)w1 << 16);
            }
            uint4 o = {uu[0], uu[1], uu[2], uu[3]};
            size_t a = ((size_t)((bl * 8 + h_base + hl) * 256 + n_tr * 8 + s)) * 1024 + d * 16 + lb * 8;
            *(uint4*)(dst + a) = o;
        }
    } else {
        // V stored feature-major: [bh][dl][ns]
        for (int idx = tid; idx < 2048; idx += 256) {
            int l = idx & 15, d = (idx >> 4) & 63, hl = idx >> 10;
            uint4 o = *(const uint4*)&ct[hl * 64 + d][l * 8];
            size_t a = ((size_t)((bl * 8 + h_base + hl) * 1024 + d * 16 + l)) * 256 + n_tr * 8;
            *(uint4*)(vb + a) = o;
        }
    }
}

// ---------- token norms |q|^2, |k|^2 ----------
__global__ __launch_bounds__(256) void norm_kernel(const unsigned short* __restrict__ qb,
    const unsigned short* __restrict__ kb, float* __restrict__ nq, float* __restrict__ nk)
{
    const int tok = blockIdx.x * 4 + (threadIdx.x >> 6);
    const int lane = threadIdx.x & 63;
    const unsigned short* src = blockIdx.y ? kb : qb;
    float* dst = blockIdx.y ? nk : nq;
    const uint4* p = (const uint4*)(src + (size_t)tok * 1024 + lane * 16);
    float s = 0.f;
    #pragma unroll
    for (int r = 0; r < 2; ++r) {
        float f[8]; unpack8(p[r], f);
        #pragma unroll
        for (int e = 0; e < 8; ++e) s = fmaf(f[e], f[e], s);
    }
    #pragma unroll
    for (int m = 32; m; m >>= 1) s += __shfl_xor(s, m);
    if (lane == 0) dst[tok] = s;
}

// ---------- attn weights via MFMA: S=QK^T, W=rsqrt(nq+nk-2S) ----------
// grid (2,2,CH*8), block 256
__global__ __launch_bounds__(256) void attnw_mfma(const unsigned short* __restrict__ qb,
    const unsigned short* __restrict__ kb, const float* __restrict__ nq,
    const float* __restrict__ nk, unsigned short* __restrict__ attn)
{
    __shared__ __align__(16) unsigned short q_s[128][136];
    __shared__ __align__(16) unsigned short k_s[128][136];
    const int bh = blockIdx.z, i0 = blockIdx.y * 128, j0 = blockIdx.x * 128;
    const int tid = threadIdx.x, w = tid >> 6, lane = tid & 63;
    const int wi = w >> 1, wj = w & 1;
    const int lrow = lane & 15, lko = (lane >> 4) * 8;
    f32x4 acc[4][4];
    #pragma unroll
    for (int m = 0; m < 4; ++m)
        #pragma unroll
        for (int n = 0; n < 4; ++n) acc[m][n] = (f32x4)0.f;
    const size_t tb = (size_t)bh * 262144;
    for (int fc = 0; fc < 8; ++fc) {
        __syncthreads();
        for (int idx = tid; idx < 2048; idx += 256) {
            int r = idx >> 4, c8 = (idx & 15) * 8;
            *(uint4*)&q_s[r][c8] = *(const uint4*)(qb + tb + (size_t)(i0 + r) * 1024 + fc * 128 + c8);
            *(uint4*)&k_s[r][c8] = *(const uint4*)(kb + tb + (size_t)(j0 + r) * 1024 + fc * 128 + c8);
        }
        __syncthreads();
        #pragma unroll
        for (int ks = 0; ks < 4; ++ks) {
            bf16x8 a[4], b[4];
            #pragma unroll
            for (int m = 0; m < 4; ++m) a[m] = *(const bf16x8*)&q_s[wi * 64 + m * 16 + lrow][ks * 32 + lko];
            #pragma unroll
            for (int n = 0; n < 4; ++n) b[n] = *(const bf16x8*)&k_s[wj * 64 + n * 16 + lrow][ks * 32 + lko];
            #pragma unroll
            for (int m = 0; m < 4; ++m)
                #pragma unroll
                for (int n = 0; n < 4; ++n)
                    acc[m][n] = __builtin_amdgcn_mfma_f32_16x16x32_bf16(a[m], b[n], acc[m][n], 0, 0, 0);
        }
    }
    float nqv[4][4], nkv[4];
    #pragma unroll
    for (int m = 0; m < 4; ++m)
        #pragma unroll
        for (int r = 0; r < 4; ++r)
            nqv[m][r] = nq[bh * 256 + i0 + wi * 64 + m * 16 + (lane >> 4) * 4 + r];
    #pragma unroll
    for (int n = 0; n < 4; ++n)
        nkv[n] = nk[bh * 256 + j0 + wj * 64 + n * 16 + lrow];
    __syncthreads();
    #pragma unroll
    for (int m = 0; m < 4; ++m)
        #pragma unroll
        for (int n = 0; n < 4; ++n)
            #pragma unroll
            for (int r = 0; r < 4; ++r) {
                float sq = nqv[m][r] + nkv[n] - 2.f * acc[m][n][r];
                q_s[wi * 64 + m * 16 + (lane >> 4) * 4 + r][wj * 64 + n * 16 + lrow] =
                    f2bf(rsqrtf(fmaxf(sq, 1e-12f)));
            }
    __syncthreads();
    for (int idx = tid; idx < 2048; idx += 256) {
        int r = idx >> 4, c8 = (idx & 15) * 8;
        *(uint4*)(attn + (size_t)bh * 65536 + (size_t)(i0 + r) * 256 + j0 + c8) =
            *(const uint4*)&q_s[r][c8];
    }
}

// ---------- out = attn @ V via MFMA; writes umat[bn_local][lt][cin=512] ----------
// grid (8,2,CH*8), block 256
__global__ __launch_bounds__(256) void pv_mfma(const unsigned short* __restrict__ attn,
    const unsigned short* __restrict__ vb, unsigned short* __restrict__ umat)
{
    __shared__ __align__(16) unsigned short a_s[128][136];
    __shared__ __align__(16) unsigned short b_s[128][136];
    const int bh = blockIdx.z, i0 = blockIdx.y * 128, f0 = blockIdx.x * 128;
    const int tid = threadIdx.x, w = tid >> 6, lane = tid & 63;
    const int wi = w >> 1, wf = w & 1;
    const int lrow = lane & 15, lko = (lane >> 4) * 8;
    f32x4 acc[4][4];
    #pragma unroll
    for (int m = 0; m < 4; ++m)
        #pragma unroll
        for (int n = 0; n < 4; ++n) acc[m][n] = (f32x4)0.f;
    for (int jc = 0; jc < 2; ++jc) {
        __syncthreads();
        for (int idx = tid; idx < 2048; idx += 256) {
            int r = idx >> 4, c8 = (idx & 15) * 8;
            *(uint4*)&a_s[r][c8] = *(const uint4*)(attn + (size_t)bh * 65536 + (size_t)(i0 + r) * 256 + jc * 128 + c8);
            *(uint4*)&b_s[r][c8] = *(const uint4*)(vb + (size_t)bh * 262144 + (size_t)(f0 + r) * 256 + jc * 128 + c8);
        }
        __syncthreads();
        #pragma unroll
        for (int ks = 0; ks < 4; ++ks) {
            bf16x8 a[4], b[4];
            #pragma unroll
            for (int m = 0; m < 4; ++m) a[m] = *(const bf16x8*)&a_s[wi * 64 + m * 16 + lrow][ks * 32 + lko];
            #pragma unroll
            for (int n = 0; n < 4; ++n) b[n] = *(const bf16x8*)&b_s[wf * 64 + n * 16 + lrow][ks * 32 + lko];
            #pragma unroll
            for (int m = 0; m < 4; ++m)
                #pragma unroll
                for (int n = 0; n < 4; ++n)
                    acc[m][n] = __builtin_amdgcn_mfma_f32_16x16x32_bf16(a[m], b[n], acc[m][n], 0, 0, 0);
        }
    }
    __syncthreads();
    #pragma unroll
    for (int m = 0; m < 4; ++m)
        #pragma unroll
        for (int n = 0; n < 4; ++n)
            #pragma unroll
            for (int r = 0; r < 4; ++r)
                a_s[wi * 64 + m * 16 + (lane >> 4) * 4 + r][wf * 64 + n * 16 + lrow] = f2bf(acc[m][n][r]);
    __syncthreads();
    // scatter: umat[(b*32+n)][lt = l*8+s][cin = h*64 + f0/16 + dd], dd=0..7 per uint4
    const int bl = bh >> 3, h = bh & 7;
    const int cinb = h * 64 + (f0 >> 4);
    for (int idx = tid; idx < 2048; idx += 256) {
        int r = idx >> 4;            // i-local
        int l = idx & 15;            // f & 15
        int i = i0 + r;
        int nn = i >> 3, s = i & 7;
        int lt = l * 8 + s;
        unsigned int uu[4];
        #pragma unroll
        for (int e = 0; e < 4; ++e) {
            unsigned short w0 = a_s[r][(e * 2 + 0) * 16 + l];
            unsigned short w1 = a_s[r][(e * 2 + 1) * 16 + l];
            uu[e] = (unsigned int)w0 | ((unsigned int)w1 << 16);
        }
        uint4 o = {uu[0], uu[1], uu[2], uu[3]};
        *(uint4*)(umat + ((size_t)(bl * 32 + nn) * 128 + lt) * 512 + cinb) = o;
    }
}

// ---------- merge conv via MFMA (Cin=512,K=3) + residual -> x2 ----------
// grid CH*32, block 256
__global__ __launch_bounds__(256) void merge_mfma(const unsigned short* __restrict__ umat,
    const float* __restrict__ x, const unsigned short* __restrict__ wmg,
    const float* __restrict__ bias, float* __restrict__ x2, int b0)
{
    __shared__ __align__(16) unsigned short ut[130][136];
    __shared__ __align__(16) unsigned short wls[3][64][136];
    const int sl = blockIdx.x, tid = threadIdx.x;
    const int bn = b0 * 32 + sl;
    const int w = tid >> 6, lane = tid & 63;
    const int lrow = lane & 15, lko = (lane >> 4) * 8, q4 = lane >> 4;
    if (tid < 128) { ut[0][tid] = 0; ut[129][tid] = 0; }
    f32x4 acc[2][4];
    #pragma unroll
    for (int m = 0; m < 2; ++m)
        #pragma unroll
        for (int n = 0; n < 4; ++n) acc[m][n] = (f32x4)0.f;
    for (int c4 = 0; c4 < 4; ++c4) {
        __syncthreads();
        for (int idx = tid; idx < 2048; idx += 256) {
            int lt = idx >> 4, ci8 = (idx & 15) * 8;
            *(uint4*)&ut[1 + lt][ci8] =
                *(const uint4*)(umat + ((size_t)sl * 128 + lt) * 512 + c4 * 128 + ci8);
        }
        for (int idx = tid; idx < 3072; idx += 256) {
            int k = idx >> 10, rem = idx & 1023;
            int co = rem >> 4, ci8 = (rem & 15) * 8;
            *(uint4*)&wls[k][co][ci8] =
                *(const uint4*)(wmg + (size_t)k * 32768 + co * 512 + c4 * 128 + ci8);
        }
        __syncthreads();
        #pragma unroll
        for (int k = 0; k < 3; ++k) {
            #pragma unroll
            for (int kc = 0; kc < 4; ++kc) {
                bf16x8 a[2], b[4];
                a[0] = *(const bf16x8*)&wls[k][(w >> 1) * 32 + lrow][kc * 32 + lko];
                a[1] = *(const bf16x8*)&wls[k][(w >> 1) * 32 + 16 + lrow][kc * 32 + lko];
                #pragma unroll
                for (int n = 0; n < 4; ++n)
                    b[n] = *(const bf16x8*)&ut[(w & 1) * 64 + n * 16 + lrow + k][kc * 32 + lko];
                #pragma unroll
                for (int m = 0; m < 2; ++m)
                    #pragma unroll
                    for (int n = 0; n < 4; ++n)
                        acc[m][n] = __builtin_amdgcn_mfma_f32_16x16x32_bf16(a[m], b[n], acc[m][n], 0, 0, 0);
            }
        }
    }
    #pragma unroll
    for (int m = 0; m < 2; ++m) {
        int cb = (w >> 1) * 32 + m * 16 + q4 * 4;
        float bv[4];
        #pragma unroll
        for (int r = 0; r < 4; ++r) bv[r] = bias[cb + r];
        #pragma unroll
        for (int n = 0; n < 4; ++n) {
            int lt = (w & 1) * 64 + n * 16 + lrow;
            #pragma unroll
            for (int r = 0; r < 4; ++r) {
                size_t a = (size_t)bn * 8192 + (size_t)(cb + r) * 128 + lt;
                x2[a] = acc[m][n][r] + bv[r] + x[a];
            }
        }
    }
}

// ---------- ff1 conv via MFMA (Cin=64->256) + GN2 on the fly + swish -> h[bn][lt][256] ----------
// grid (2, 512), block 256
__global__ __launch_bounds__(256) void ff1_mfma(const float* __restrict__ x2,
    const float* __restrict__ sa, const float* __restrict__ sb,
    const unsigned short* __restrict__ wf1, const float* __restrict__ bias,
    unsigned short* __restrict__ hb)
{
    __shared__ __align__(16) unsigned short xt[130][72];
    __shared__ __align__(16) unsigned short wls[3][128][72];
    const int mc = blockIdx.x, bn = blockIdx.y, tid = threadIdx.x;
    for (int idx = tid; idx < 8192; idx += 256) {
        int lt = idx & 127, c = idx >> 7;
        float v = x2[(size_t)bn * 8192 + c * 128 + lt] * sa[bn * 64 + c] + sb[bn * 64 + c];
        xt[1 + lt][c] = f2bf(v);
    }
    if (tid < 64) { xt[0][tid] = 0; xt[129][tid] = 0; }
    for (int idx = tid; idx < 3072; idx += 256) {
        int k = idx >> 10, rem = idx & 1023, co = rem >> 3, ci8 = (rem & 7) * 8;
        *(uint4*)&wls[k][co][ci8] =
            *(const uint4*)(wf1 + (size_t)k * 16384 + (size_t)(mc * 128 + co) * 64 + ci8);
    }
    __syncthreads();
    const int w = tid >> 6, lane = tid & 63;
    const int lrow = lane & 15, lko = (lane >> 4) * 8, q4 = lane >> 4;
    f32x4 acc[2][8];
    #pragma unroll
    for (int m = 0; m < 2; ++m)
        #pragma unroll
        for (int n = 0; n < 8; ++n) acc[m][n] = (f32x4)0.f;
    #pragma unroll
    for (int k = 0; k < 3; ++k) {
        #pragma unroll
        for (int kc = 0; kc < 2; ++kc) {
            bf16x8 a0 = *(const bf16x8*)&wls[k][w * 32 + lrow][kc * 32 + lko];
            bf16x8 a1 = *(const bf16x8*)&wls[k][w * 32 + 16 + lrow][kc * 32 + lko];
            #pragma unroll
            for (int n = 0; n < 8; ++n) {
                bf16x8 b = *(const bf16x8*)&xt[n * 16 + lrow + k][kc * 32 + lko];
                acc[0][n] = __builtin_amdgcn_mfma_f32_16x16x32_bf16(a0, b, acc[0][n], 0, 0, 0);
                acc[1][n] = __builtin_amdgcn_mfma_f32_16x16x32_bf16(a1, b, acc[1][n], 0, 0, 0);
            }
        }
    }
    // swish epilogue; h[bn][lt][cout] with 4 consecutive couts per store
    #pragma unroll
    for (int m = 0; m < 2; ++m) {
        int rb = w * 32 + m * 16 + q4 * 4;     // cout local base
        float bv[4];
        #pragma unroll
        for (int r = 0; r < 4; ++r) bv[r] = bias[mc * 128 + rb + r];
        #pragma unroll
        for (int n = 0; n < 8; ++n) {
            int lt = n * 16 + lrow;
            float sws[4];
            #pragma unroll
            for (int r = 0; r < 4; ++r) {
                float t = acc[m][n][r] + bv[r];
                sws[r] = t / (1.f + __expf(-t));
            }
            uint2 o = {pack2(sws[0], sws[1]), pack2(sws[2], sws[3])};
            *(uint2*)(hb + (size_t)bn * 32768 + (size_t)lt * 256 + mc * 128 + rb) = o;
        }
    }
}

// ---------- ff2 conv via MFMA (Cin=256->64) + residual -> y ----------
// grid 512, block 256
__global__ __launch_bounds__(256) void ff2_mfma(const unsigned short* __restrict__ hb,
    const float* __restrict__ x2, const unsigned short* __restrict__ wf2,
    const float* __restrict__ bias, float* __restrict__ y)
{
    __shared__ __align__(16) unsigned short ut[130][136];
    __shared__ __align__(16) unsigned short wls[3][64][136];
    const int bn = blockIdx.x, tid = threadIdx.x;
    const int w = tid >> 6, lane = tid & 63;
    const int lrow = lane & 15, lko = (lane >> 4) * 8, q4 = lane >> 4;
    if (tid < 128) { ut[0][tid] = 0; ut[129][tid] = 0; }
    f32x4 acc[2][4];
    #pragma unroll
    for (int m = 0; m < 2; ++m)
        #pragma unroll
        for (int n = 0; n < 4; ++n) acc[m][n] = (f32x4)0.f;
    for (int c2 = 0; c2 < 2; ++c2) {
        __syncthreads();
        for (int idx = tid; idx < 2048; idx += 256) {
            int lt = idx >> 4, ci8 = (idx & 15) * 8;
            *(uint4*)&ut[1 + lt][ci8] =
                *(const uint4*)(hb + (size_t)bn * 32768 + (size_t)lt * 256 + c2 * 128 + ci8);
        }
        for (int idx = tid; idx < 3072; idx += 256) {
            int k = idx >> 10, rem = idx & 1023;
            int co = rem >> 4, ci8 = (rem & 15) * 8;
            *(uint4*)&wls[k][co][ci8] =
                *(const uint4*)(wf2 + (size_t)k * 16384 + co * 256 + c2 * 128 + ci8);
        }
        __syncthreads();
        #pragma unroll
        for (int k = 0; k < 3; ++k) {
            #pragma unroll
            for (int kc = 0; kc < 4; ++kc) {
                bf16x8 a[2], b[4];
                a[0] = *(const bf16x8*)&wls[k][(w >> 1) * 32 + lrow][kc * 32 + lko];
                a[1] = *(const bf16x8*)&wls[k][(w >> 1) * 32 + 16 + lrow][kc * 32 + lko];
                #pragma unroll
                for (int n = 0; n < 4; ++n)
                    b[n] = *(const bf16x8*)&ut[(w & 1) * 64 + n * 16 + lrow + k][kc * 32 + lko];
                #pragma unroll
                for (int m = 0; m < 2; ++m)
                    #pragma unroll
                    for (int n = 0; n < 4; ++n)
                        acc[m][n] = __builtin_amdgcn_mfma_f32_16x16x32_bf16(a[m], b[n], acc[m][n], 0, 0, 0);
            }
        }
    }
    #pragma unroll
    for (int m = 0; m < 2; ++m) {
        int cb = (w >> 1) * 32 + m * 16 + q4 * 4;
        float bv[4];
        #pragma unroll
        for (int r = 0; r < 4; ++r) bv[r] = bias[cb + r];
        #pragma unroll
        for (int n = 0; n < 4; ++n) {
            int lt = (w & 1) * 64 + n * 16 + lrow;
            #pragma unroll
            for (int r = 0; r < 4; ++r) {
                size_t a = (size_t)bn * 8192 + (size_t)(cb + r) * 128 + lt;
                y[a] = acc[m][n][r] + bv[r] + x2[a];
            }
        }
    }
}

// ---------- launch ----------
extern "C" void kernel_launch(void* const* d_in, const int* in_sizes, int n_in,
                              void* d_out, int out_size, void* d_ws, size_t ws_size,
                              hipStream_t stream) {
    (void)in_sizes; (void)n_in; (void)out_size;
    const float* x     = (const float*)d_in[0];
    const float* gn1_g = (const float*)d_in[1];
    const float* gn1_b = (const float*)d_in[2];
    const float* w_qkv = (const float*)d_in[3];
    const float* b_qkv = (const float*)d_in[4];
    const float* w_mg  = (const float*)d_in[5];
    const float* b_mg  = (const float*)d_in[6];
    const float* gn2_g = (const float*)d_in[7];
    const float* gn2_b = (const float*)d_in[8];
    const float* w_f1  = (const float*)d_in[9];
    const float* b_f1  = (const float*)d_in[10];
    const float* w_f2  = (const float*)d_in[11];
    const float* b_f2  = (const float*)d_in[12];
    float* y = (float*)d_out;

    char* ws = (char*)d_ws;
    const size_t OFF_SA1 = 0;
    const size_t OFF_SB1 = 131072;
    const size_t OFF_SA2 = 262144;
    const size_t OFF_SB2 = 393216;
    const size_t OFF_NQ  = 524288;
    const size_t OFF_NK  = 655360;
    const size_t OFF_WQ  = 786432;        // 589,824 B
    const size_t OFF_WMG = 1376256;       // 196,608 B
    const size_t OFF_WF1 = 1572864;       // 98,304 B
    const size_t OFF_WF2 = 1671168;       // 98,304 B
    const size_t OFF_X2  = 2097152;       // 16.78 MB
    const size_t OFF_CHUNK = 20971520;    // 20 MB
    const size_t H_BYTES = 33554432;      // h buffer 33.55 MB

    int CH = 1;
    {
        const int cands[5] = {16, 8, 4, 2, 1};
        for (int ci = 0; ci < 5; ++ci) {
            int c = cands[ci];
            size_t qsz = (size_t)c * 4194304;
            size_t asz = (size_t)c * 1048576;
            size_t body = 3 * qsz + asz;
            if (body < H_BYTES) body = H_BYTES;
            if (OFF_CHUNK + body <= ws_size) { CH = c; break; }
        }
    }
    const size_t QSZ = (size_t)CH * 4194304;
    const size_t OFF_Q    = OFF_CHUNK;
    const size_t OFF_K    = OFF_Q + QSZ;
    const size_t OFF_V    = OFF_K + QSZ;
    const size_t OFF_ATTN = OFF_V + QSZ;

    float* sa1 = (float*)(ws + OFF_SA1);
    float* sb1 = (float*)(ws + OFF_SB1);
    float* sa2 = (float*)(ws + OFF_SA2);
    float* sb2 = (float*)(ws + OFF_SB2);
    float* nqp = (float*)(ws + OFF_NQ);
    float* nkp = (float*)(ws + OFF_NK);
    unsigned short* wqb  = (unsigned short*)(ws + OFF_WQ);
    unsigned short* wmgb = (unsigned short*)(ws + OFF_WMG);
    unsigned short* wf1b = (unsigned short*)(ws + OFF_WF1);
    unsigned short* wf2b = (unsigned short*)(ws + OFF_WF2);
    float* x2  = (float*)(ws + OFF_X2);
    unsigned short* qb   = (unsigned short*)(ws + OFF_Q);
    unsigned short* kb   = (unsigned short*)(ws + OFF_K);
    unsigned short* vbuf = (unsigned short*)(ws + OFF_V);
    unsigned short* attn = (unsigned short*)(ws + OFF_ATTN);
    unsigned short* umat = (unsigned short*)(ws + OFF_Q);      // reuse q (dead after attnw)
    unsigned short* hbuf = (unsigned short*)(ws + OFF_CHUNK);  // reuse chunk region after loop

    gnstats_kernel<<<512, 256, 0, stream>>>(x, gn1_g, gn1_b, sa1, sb1);
    prep_w_kernel<<<384, 256, 0, stream>>>(w_qkv, wqb, 98304);
    prep_w_kernel<<<128, 256, 0, stream>>>(w_mg,  wmgb, 32768);
    prep_w_kernel<<<64,  256, 0, stream>>>(w_f1,  wf1b, 16384);
    prep_w_kernel<<<64,  256, 0, stream>>>(w_f2,  wf2b, 16384);
    const int nch = 16 / CH;
    for (int cidx = 0; cidx < nch; ++cidx) {
        int b0 = cidx * CH;
        conv_qkv_mfma<<<dim3(12, CH * 32), 256, 0, stream>>>(x, sa1, sb1, wqb, b_qkv, qb, kb, vbuf, b0);
        norm_kernel<<<dim3(CH * 512, 2), 256, 0, stream>>>(qb, kb, nqp, nkp);
        attnw_mfma<<<dim3(2, 2, CH * 8), 256, 0, stream>>>(qb, kb, nqp, nkp, attn);
        pv_mfma<<<dim3(8, 2, CH * 8), 256, 0, stream>>>(attn, vbuf, umat);
        merge_mfma<<<CH * 32, 256, 0, stream>>>(umat, x, wmgb, b_mg, x2, b0);
    }
    gnstats_kernel<<<512, 256, 0, stream>>>(x2, gn2_g, gn2_b, sa2, sb2);
    ff1_mfma<<<dim3(2, 512), 256, 0, stream>>>(x2, sa2, sb2, wf1b, b_f1, hbuf);
    ff2_mfma<<<512, 256, 0, stream>>>(hbuf, x2, wf2b, b_f2, y);
}

// Round 5
// 329.399 us; speedup vs baseline: 6.4137x; 1.3089x over previous
//
#include <hip/hip_runtime.h>
#include <hip/hip_bf16.h>

#define DEV __device__ __forceinline__

typedef __attribute__((ext_vector_type(8))) __bf16 bf16x8;
typedef __attribute__((ext_vector_type(4))) float f32x4;

// ---------- bf16 helpers (bit-level) ----------
DEV float bfu(unsigned short u) { return __uint_as_float((unsigned int)u << 16); }
DEV unsigned short f2bf(float f) {
    union { float f; unsigned int u; } cv; cv.f = f;
    unsigned int u = cv.u;
    unsigned int r = (u + 0x7fffu + ((u >> 16) & 1u)) >> 16;  // RNE
    return (unsigned short)r;
}
DEV unsigned int pack2(float a, float b) {
    return (unsigned int)f2bf(a) | ((unsigned int)f2bf(b) << 16);
}

// dims: B=16 N=32 D=64 H=8 S=8 LT=128 DE=256 L=16
// BN=512 BH=128 NS=256 DL=1024 DQKV=1536

// ---------- GroupNorm stats ----------
__global__ __launch_bounds__(256) void gnstats_kernel(const float* __restrict__ src,
    const float* __restrict__ gamma, const float* __restrict__ beta,
    float* __restrict__ sa, float* __restrict__ sb)
{
    __shared__ float gsum[8], gsq[8];
    const int s = blockIdx.x, tid = threadIdx.x;
    const int g = tid >> 5, il = tid & 31;
    const float* p = src + (size_t)s * 8192 + g * 1024 + il;
    float sm = 0.f, sq = 0.f;
    #pragma unroll
    for (int m = 0; m < 32; ++m) {
        float v = p[m * 32];
        sm += v; sq += v * v;
    }
    #pragma unroll
    for (int m = 16; m; m >>= 1) { sm += __shfl_xor(sm, m); sq += __shfl_xor(sq, m); }
    if (il == 0) { gsum[g] = sm; gsq[g] = sq; }
    __syncthreads();
    if (tid < 64) {
        int gg = tid >> 3;
        float mu = gsum[gg] * (1.f / 1024.f);
        float var = gsq[gg] * (1.f / 1024.f) - mu * mu;
        float a = gamma[tid] * rsqrtf(var + 1e-5f);
        sa[s * 64 + tid] = a;
        sb[s * 64 + tid] = beta[tid] - mu * a;
    }
}

// ---------- xprep: xnt[bn][130][64] = bf16(GN(x))^T with zero halo rows ----------
// grid 512, block 256
__global__ __launch_bounds__(256) void xprep_kernel(const float* __restrict__ src,
    const float* __restrict__ sa, const float* __restrict__ sb,
    unsigned short* __restrict__ xnt)
{
    __shared__ __align__(16) float sx[64][133];
    __shared__ float la[64], lb[64];
    const int s = blockIdx.x, tid = threadIdx.x;
    if (tid < 64) { la[tid] = sa[s * 64 + tid]; lb[tid] = sb[s * 64 + tid]; }
    for (int idx = tid; idx < 8192; idx += 256) {
        int c = idx >> 7, lt = idx & 127;
        sx[c][lt] = src[(size_t)s * 8192 + idx];
    }
    __syncthreads();
    for (int idx = tid; idx < 8320; idx += 256) {
        int row = idx >> 6, c = idx & 63;
        float v = 0.f;
        if (row >= 1 && row <= 128) v = sx[c][row - 1] * la[c] + lb[c];
        xnt[(size_t)s * 8320 + idx] = f2bf(v);
    }
}

// ---------- generic weight prep: src[i][k] (k innermost) -> dst[k][i] bf16 ----------
__global__ __launch_bounds__(256) void prep_w_kernel(const float* __restrict__ w,
    unsigned short* __restrict__ dst, int n)
{
    int i = blockIdx.x * 256 + threadIdx.x;
    if (i < n) {
        #pragma unroll
        for (int k = 0; k < 3; ++k)
            dst[k * n + i] = f2bf(w[(size_t)i * 3 + k]);
    }
}

// ---------- QKV conv via MFMA; weights in regs; fused token norms ----------
// grid (12, CH*32), block 256 (4 waves)
__global__ __launch_bounds__(256, 3) void conv_qkv_mfma(
    const unsigned short* __restrict__ xnt,
    const unsigned short* __restrict__ wq, const float* __restrict__ bias,
    unsigned short* __restrict__ qb, unsigned short* __restrict__ kb,
    unsigned short* __restrict__ vb, float* __restrict__ nq, float* __restrict__ nk,
    int b0)
{
    __shared__ __align__(16) char smem[34816];
    unsigned short (*xt)[72]  = (unsigned short(*)[72])smem;   // [130][72]
    unsigned short (*ct)[136] = (unsigned short(*)[136])smem;  // [128][136] overlay (after MFMA)

    const int mc = blockIdx.x, sl = blockIdx.y, tid = threadIdx.x;
    const int bn = b0 * 32 + sl;
    const int w = tid >> 6, lane = tid & 63;
    const int lrow = lane & 15, lko = (lane >> 4) * 8, q4 = lane >> 4;

    // A fragments straight from global (L2-hot; same for all scene blocks)
    bf16x8 af[3][2][2];
    #pragma unroll
    for (int k = 0; k < 3; ++k)
        #pragma unroll
        for (int kc = 0; kc < 2; ++kc)
            #pragma unroll
            for (int m = 0; m < 2; ++m)
                af[k][kc][m] = *(const bf16x8*)(wq + (size_t)k * 98304 +
                    (size_t)(mc * 128 + w * 32 + m * 16 + lrow) * 64 + kc * 32 + lko);

    // stage x^T tile (linear copy, 1040 uint4)
    for (int idx = tid; idx < 1040; idx += 256)
        *(uint4*)&xt[idx >> 3][(idx & 7) * 8] = *(const uint4*)(xnt + (size_t)bn * 8320 + idx * 8);
    __syncthreads();

    f32x4 acc[2][8];
    #pragma unroll
    for (int m = 0; m < 2; ++m)
        #pragma unroll
        for (int n = 0; n < 8; ++n) acc[m][n] = (f32x4)0.f;
    #pragma unroll
    for (int k = 0; k < 3; ++k) {
        #pragma unroll
        for (int kc = 0; kc < 2; ++kc) {
            #pragma unroll
            for (int n = 0; n < 8; ++n) {
                bf16x8 b = *(const bf16x8*)&xt[n * 16 + lrow + k][kc * 32 + lko];
                acc[0][n] = __builtin_amdgcn_mfma_f32_16x16x32_bf16(af[k][kc][0], b, acc[0][n], 0, 0, 0);
                acc[1][n] = __builtin_amdgcn_mfma_f32_16x16x32_bf16(af[k][kc][1], b, acc[1][n], 0, 0, 0);
            }
        }
    }
    __syncthreads();   // xt dead; reuse as ct
    const int c0 = mc * 128;
    float bv[2][4];
    #pragma unroll
    for (int m = 0; m < 2; ++m)
        #pragma unroll
        for (int r = 0; r < 4; ++r)
            bv[m][r] = bias[c0 + w * 32 + m * 16 + q4 * 4 + r];
    #pragma unroll
    for (int m = 0; m < 2; ++m)
        #pragma unroll
        for (int n = 0; n < 8; ++n)
            #pragma unroll
            for (int r = 0; r < 4; ++r)
                ct[w * 32 + m * 16 + q4 * 4 + r][n * 16 + lrow] =
                    f2bf(acc[m][n][r] + bv[m][r]);
    __syncthreads();
    const int t = mc >> 2, h_base = (mc & 3) * 2;
    const int bl = sl >> 5, n_tr = sl & 31;
    if (t < 2) {
        unsigned short* dst = t ? kb : qb;
        for (int idx = tid; idx < 2048; idx += 256) {
            int lb = idx & 1;
            int d  = (idx >> 1) & 63;
            int s  = (idx >> 7) & 7;
            int hl = idx >> 10;
            unsigned int uu[4];
            #pragma unroll
            for (int e2 = 0; e2 < 4; ++e2) {
                unsigned short w0 = ct[hl * 64 + d][(lb * 8 + e2 * 2) * 8 + s];
                unsigned short w1 = ct[hl * 64 + d][(lb * 8 + e2 * 2 + 1) * 8 + s];
                uu[e2] = (unsigned int)w0 | ((unsigned int)w1 << 16);
            }
            uint4 o = {uu[0], uu[1], uu[2], uu[3]};
            size_t a = ((size_t)((bl * 8 + h_base + hl) * 256 + n_tr * 8 + s)) * 1024 + d * 16 + lb * 8;
            *(uint4*)(dst + a) = o;
        }
        // fused token norms: 16 complete tokens in ct; thread (tk, l) sums over d
        float* ndst = t ? nk : nq;
        const int tk = tid >> 4, l = tid & 15;
        const int hl = tk >> 3, sS = tk & 7;
        float s2 = 0.f;
        for (int d = 0; d < 64; ++d) {
            float v = bfu(ct[hl * 64 + d][l * 8 + sS]);
            s2 = fmaf(v, v, s2);
        }
        #pragma unroll
        for (int m = 8; m; m >>= 1) s2 += __shfl_xor(s2, m);
        if (l == 0)
            ndst[(bl * 8 + h_base + hl) * 256 + n_tr * 8 + sS] = s2;
    } else {
        // V stored feature-major: [bh][dl][ns]
        for (int idx = tid; idx < 2048; idx += 256) {
            int l = idx & 15, d = (idx >> 4) & 63, hl = idx >> 10;
            uint4 o = *(const uint4*)&ct[hl * 64 + d][l * 8];
            size_t a = ((size_t)((bl * 8 + h_base + hl) * 1024 + d * 16 + l)) * 256 + n_tr * 8;
            *(uint4*)(vb + a) = o;
        }
    }
}

// ---------- attn weights via MFMA: S=QK^T, W=rsqrt(nq+nk-2S) ----------
// grid (2,2,CH*8), block 256
__global__ __launch_bounds__(256) void attnw_mfma(const unsigned short* __restrict__ qb,
    const unsigned short* __restrict__ kb, const float* __restrict__ nq,
    const float* __restrict__ nk, unsigned short* __restrict__ attn)
{
    __shared__ __align__(16) unsigned short q_s[128][136];
    __shared__ __align__(16) unsigned short k_s[128][136];
    const int bh = blockIdx.z, i0 = blockIdx.y * 128, j0 = blockIdx.x * 128;
    const int tid = threadIdx.x, w = tid >> 6, lane = tid & 63;
    const int wi = w >> 1, wj = w & 1;
    const int lrow = lane & 15, lko = (lane >> 4) * 8;
    f32x4 acc[4][4];
    #pragma unroll
    for (int m = 0; m < 4; ++m)
        #pragma unroll
        for (int n = 0; n < 4; ++n) acc[m][n] = (f32x4)0.f;
    const size_t tb = (size_t)bh * 262144;
    for (int fc = 0; fc < 8; ++fc) {
        __syncthreads();
        for (int idx = tid; idx < 2048; idx += 256) {
            int r = idx >> 4, c8 = (idx & 15) * 8;
            *(uint4*)&q_s[r][c8] = *(const uint4*)(qb + tb + (size_t)(i0 + r) * 1024 + fc * 128 + c8);
            *(uint4*)&k_s[r][c8] = *(const uint4*)(kb + tb + (size_t)(j0 + r) * 1024 + fc * 128 + c8);
        }
        __syncthreads();
        #pragma unroll
        for (int ks = 0; ks < 4; ++ks) {
            bf16x8 a[4], b[4];
            #pragma unroll
            for (int m = 0; m < 4; ++m) a[m] = *(const bf16x8*)&q_s[wi * 64 + m * 16 + lrow][ks * 32 + lko];
            #pragma unroll
            for (int n = 0; n < 4; ++n) b[n] = *(const bf16x8*)&k_s[wj * 64 + n * 16 + lrow][ks * 32 + lko];
            #pragma unroll
            for (int m = 0; m < 4; ++m)
                #pragma unroll
                for (int n = 0; n < 4; ++n)
                    acc[m][n] = __builtin_amdgcn_mfma_f32_16x16x32_bf16(a[m], b[n], acc[m][n], 0, 0, 0);
        }
    }
    float nqv[4][4], nkv[4];
    #pragma unroll
    for (int m = 0; m < 4; ++m)
        #pragma unroll
        for (int r = 0; r < 4; ++r)
            nqv[m][r] = nq[bh * 256 + i0 + wi * 64 + m * 16 + (lane >> 4) * 4 + r];
    #pragma unroll
    for (int n = 0; n < 4; ++n)
        nkv[n] = nk[bh * 256 + j0 + wj * 64 + n * 16 + lrow];
    __syncthreads();
    #pragma unroll
    for (int m = 0; m < 4; ++m)
        #pragma unroll
        for (int n = 0; n < 4; ++n)
            #pragma unroll
            for (int r = 0; r < 4; ++r) {
                float sq = nqv[m][r] + nkv[n] - 2.f * acc[m][n][r];
                q_s[wi * 64 + m * 16 + (lane >> 4) * 4 + r][wj * 64 + n * 16 + lrow] =
                    f2bf(rsqrtf(fmaxf(sq, 1e-12f)));
            }
    __syncthreads();
    for (int idx = tid; idx < 2048; idx += 256) {
        int r = idx >> 4, c8 = (idx & 15) * 8;
        *(uint4*)(attn + (size_t)bh * 65536 + (size_t)(i0 + r) * 256 + j0 + c8) =
            *(const uint4*)&q_s[r][c8];
    }
}

// ---------- out = attn @ V via MFMA; writes umat[bn_local][lt][cin=512] ----------
// grid (8,2,CH*8), block 256
__global__ __launch_bounds__(256) void pv_mfma(const unsigned short* __restrict__ attn,
    const unsigned short* __restrict__ vb, unsigned short* __restrict__ umat)
{
    __shared__ __align__(16) unsigned short a_s[128][136];
    __shared__ __align__(16) unsigned short b_s[128][136];
    const int bh = blockIdx.z, i0 = blockIdx.y * 128, f0 = blockIdx.x * 128;
    const int tid = threadIdx.x, w = tid >> 6, lane = tid & 63;
    const int wi = w >> 1, wf = w & 1;
    const int lrow = lane & 15, lko = (lane >> 4) * 8;
    f32x4 acc[4][4];
    #pragma unroll
    for (int m = 0; m < 4; ++m)
        #pragma unroll
        for (int n = 0; n < 4; ++n) acc[m][n] = (f32x4)0.f;
    for (int jc = 0; jc < 2; ++jc) {
        __syncthreads();
        for (int idx = tid; idx < 2048; idx += 256) {
            int r = idx >> 4, c8 = (idx & 15) * 8;
            *(uint4*)&a_s[r][c8] = *(const uint4*)(attn + (size_t)bh * 65536 + (size_t)(i0 + r) * 256 + jc * 128 + c8);
            *(uint4*)&b_s[r][c8] = *(const uint4*)(vb + (size_t)bh * 262144 + (size_t)(f0 + r) * 256 + jc * 128 + c8);
        }
        __syncthreads();
        #pragma unroll
        for (int ks = 0; ks < 4; ++ks) {
            bf16x8 a[4], b[4];
            #pragma unroll
            for (int m = 0; m < 4; ++m) a[m] = *(const bf16x8*)&a_s[wi * 64 + m * 16 + lrow][ks * 32 + lko];
            #pragma unroll
            for (int n = 0; n < 4; ++n) b[n] = *(const bf16x8*)&b_s[wf * 64 + n * 16 + lrow][ks * 32 + lko];
            #pragma unroll
            for (int m = 0; m < 4; ++m)
                #pragma unroll
                for (int n = 0; n < 4; ++n)
                    acc[m][n] = __builtin_amdgcn_mfma_f32_16x16x32_bf16(a[m], b[n], acc[m][n], 0, 0, 0);
        }
    }
    __syncthreads();
    #pragma unroll
    for (int m = 0; m < 4; ++m)
        #pragma unroll
        for (int n = 0; n < 4; ++n)
            #pragma unroll
            for (int r = 0; r < 4; ++r)
                a_s[wi * 64 + m * 16 + (lane >> 4) * 4 + r][wf * 64 + n * 16 + lrow] = f2bf(acc[m][n][r]);
    __syncthreads();
    const int bl = bh >> 3, h = bh & 7;
    const int cinb = h * 64 + (f0 >> 4);
    for (int idx = tid; idx < 2048; idx += 256) {
        int r = idx >> 4;
        int l = idx & 15;
        int i = i0 + r;
        int nn = i >> 3, s = i & 7;
        int lt = l * 8 + s;
        unsigned int uu[4];
        #pragma unroll
        for (int e = 0; e < 4; ++e) {
            unsigned short w0 = a_s[r][(e * 2 + 0) * 16 + l];
            unsigned short w1 = a_s[r][(e * 2 + 1) * 16 + l];
            uu[e] = (unsigned int)w0 | ((unsigned int)w1 << 16);
        }
        uint4 o = {uu[0], uu[1], uu[2], uu[3]};
        *(uint4*)(umat + ((size_t)(bl * 32 + nn) * 128 + lt) * 512 + cinb) = o;
    }
}

// ---------- merge conv via MFMA (Cin=512,K=3) + residual -> x2; weights in regs ----------
// grid CH*32, block 256
__global__ __launch_bounds__(256, 3) void merge_mfma(const unsigned short* __restrict__ umat,
    const float* __restrict__ x, const unsigned short* __restrict__ wmg,
    const float* __restrict__ bias, float* __restrict__ x2, int b0)
{
    __shared__ __align__(16) unsigned short ut[130][136];
    const int sl = blockIdx.x, tid = threadIdx.x;
    const int bn = b0 * 32 + sl;
    const int w = tid >> 6, lane = tid & 63;
    const int lrow = lane & 15, lko = (lane >> 4) * 8, q4 = lane >> 4;
    if (tid < 128) { ut[0][tid] = 0; ut[129][tid] = 0; }
    f32x4 acc[2][4];
    #pragma unroll
    for (int m = 0; m < 2; ++m)
        #pragma unroll
        for (int n = 0; n < 4; ++n) acc[m][n] = (f32x4)0.f;
    for (int c4 = 0; c4 < 4; ++c4) {
        __syncthreads();
        for (int idx = tid; idx < 2048; idx += 256) {
            int lt = idx >> 4, ci8 = (idx & 15) * 8;
            *(uint4*)&ut[1 + lt][ci8] =
                *(const uint4*)(umat + ((size_t)sl * 128 + lt) * 512 + c4 * 128 + ci8);
        }
        // A fragments from global (L2-hot)
        bf16x8 af[3][4][2];
        #pragma unroll
        for (int k = 0; k < 3; ++k)
            #pragma unroll
            for (int kc = 0; kc < 4; ++kc)
                #pragma unroll
                for (int m = 0; m < 2; ++m)
                    af[k][kc][m] = *(const bf16x8*)(wmg + (size_t)k * 32768 +
                        (size_t)((w >> 1) * 32 + m * 16 + lrow) * 512 + c4 * 128 + kc * 32 + lko);
        __syncthreads();
        #pragma unroll
        for (int k = 0; k < 3; ++k) {
            #pragma unroll
            for (int kc = 0; kc < 4; ++kc) {
                bf16x8 b[4];
                #pragma unroll
                for (int n = 0; n < 4; ++n)
                    b[n] = *(const bf16x8*)&ut[(w & 1) * 64 + n * 16 + lrow + k][kc * 32 + lko];
                #pragma unroll
                for (int m = 0; m < 2; ++m)
                    #pragma unroll
                    for (int n = 0; n < 4; ++n)
                        acc[m][n] = __builtin_amdgcn_mfma_f32_16x16x32_bf16(af[k][kc][m], b[n], acc[m][n], 0, 0, 0);
            }
        }
    }
    #pragma unroll
    for (int m = 0; m < 2; ++m) {
        int cb = (w >> 1) * 32 + m * 16 + q4 * 4;
        float bv[4];
        #pragma unroll
        for (int r = 0; r < 4; ++r) bv[r] = bias[cb + r];
        #pragma unroll
        for (int n = 0; n < 4; ++n) {
            int lt = (w & 1) * 64 + n * 16 + lrow;
            #pragma unroll
            for (int r = 0; r < 4; ++r) {
                size_t a = (size_t)bn * 8192 + (size_t)(cb + r) * 128 + lt;
                x2[a] = acc[m][n][r] + bv[r] + x[a];
            }
        }
    }
}

// ---------- ff1 conv via MFMA (Cin=64->256) + swish -> h[bn][lt][256]; weights in regs ----------
// grid (2, 512), block 256; input = precomputed xnt2
__global__ __launch_bounds__(256, 3) void ff1_mfma(const unsigned short* __restrict__ xnt,
    const unsigned short* __restrict__ wf1, const float* __restrict__ bias,
    unsigned short* __restrict__ hb)
{
    __shared__ __align__(16) unsigned short xt[130][72];
    const int mc = blockIdx.x, bn = blockIdx.y, tid = threadIdx.x;
    const int w = tid >> 6, lane = tid & 63;
    const int lrow = lane & 15, lko = (lane >> 4) * 8, q4 = lane >> 4;
    bf16x8 af[3][2][2];
    #pragma unroll
    for (int k = 0; k < 3; ++k)
        #pragma unroll
        for (int kc = 0; kc < 2; ++kc)
            #pragma unroll
            for (int m = 0; m < 2; ++m)
                af[k][kc][m] = *(const bf16x8*)(wf1 + (size_t)k * 16384 +
                    (size_t)(mc * 128 + w * 32 + m * 16 + lrow) * 64 + kc * 32 + lko);
    for (int idx = tid; idx < 1040; idx += 256)
        *(uint4*)&xt[idx >> 3][(idx & 7) * 8] = *(const uint4*)(xnt + (size_t)bn * 8320 + idx * 8);
    __syncthreads();
    f32x4 acc[2][8];
    #pragma unroll
    for (int m = 0; m < 2; ++m)
        #pragma unroll
        for (int n = 0; n < 8; ++n) acc[m][n] = (f32x4)0.f;
    #pragma unroll
    for (int k = 0; k < 3; ++k) {
        #pragma unroll
        for (int kc = 0; kc < 2; ++kc) {
            #pragma unroll
            for (int n = 0; n < 8; ++n) {
                bf16x8 b = *(const bf16x8*)&xt[n * 16 + lrow + k][kc * 32 + lko];
                acc[0][n] = __builtin_amdgcn_mfma_f32_16x16x32_bf16(af[k][kc][0], b, acc[0][n], 0, 0, 0);
                acc[1][n] = __builtin_amdgcn_mfma_f32_16x16x32_bf16(af[k][kc][1], b, acc[1][n], 0, 0, 0);
            }
        }
    }
    #pragma unroll
    for (int m = 0; m < 2; ++m) {
        int rb = w * 32 + m * 16 + q4 * 4;
        float bv[4];
        #pragma unroll
        for (int r = 0; r < 4; ++r) bv[r] = bias[mc * 128 + rb + r];
        #pragma unroll
        for (int n = 0; n < 8; ++n) {
            int lt = n * 16 + lrow;
            float sws[4];
            #pragma unroll
            for (int r = 0; r < 4; ++r) {
                float t = acc[m][n][r] + bv[r];
                sws[r] = t / (1.f + __expf(-t));
            }
            uint2 o = {pack2(sws[0], sws[1]), pack2(sws[2], sws[3])};
            *(uint2*)(hb + (size_t)bn * 32768 + (size_t)lt * 256 + mc * 128 + rb) = o;
        }
    }
}

// ---------- ff2 conv via MFMA (Cin=256->64) + residual -> y; weights in regs ----------
// grid 512, block 256
__global__ __launch_bounds__(256, 3) void ff2_mfma(const unsigned short* __restrict__ hb,
    const float* __restrict__ x2, const unsigned short* __restrict__ wf2,
    const float* __restrict__ bias, float* __restrict__ y)
{
    __shared__ __align__(16) unsigned short ut[130][136];
    const int bn = blockIdx.x, tid = threadIdx.x;
    const int w = tid >> 6, lane = tid & 63;
    const int lrow = lane & 15, lko = (lane >> 4) * 8, q4 = lane >> 4;
    if (tid < 128) { ut[0][tid] = 0; ut[129][tid] = 0; }
    f32x4 acc[2][4];
    #pragma unroll
    for (int m = 0; m < 2; ++m)
        #pragma unroll
        for (int n = 0; n < 4; ++n) acc[m][n] = (f32x4)0.f;
    for (int c2 = 0; c2 < 2; ++c2) {
        __syncthreads();
        for (int idx = tid; idx < 2048; idx += 256) {
            int lt = idx >> 4, ci8 = (idx & 15) * 8;
            *(uint4*)&ut[1 + lt][ci8] =
                *(const uint4*)(hb + (size_t)bn * 32768 + (size_t)lt * 256 + c2 * 128 + ci8);
        }
        bf16x8 af[3][4][2];
        #pragma unroll
        for (int k = 0; k < 3; ++k)
            #pragma unroll
            for (int kc = 0; kc < 4; ++kc)
                #pragma unroll
                for (int m = 0; m < 2; ++m)
                    af[k][kc][m] = *(const bf16x8*)(wf2 + (size_t)k * 16384 +
                        (size_t)((w >> 1) * 32 + m * 16 + lrow) * 256 + c2 * 128 + kc * 32 + lko);
        __syncthreads();
        #pragma unroll
        for (int k = 0; k < 3; ++k) {
            #pragma unroll
            for (int kc = 0; kc < 4; ++kc) {
                bf16x8 b[4];
                #pragma unroll
                for (int n = 0; n < 4; ++n)
                    b[n] = *(const bf16x8*)&ut[(w & 1) * 64 + n * 16 + lrow + k][kc * 32 + lko];
                #pragma unroll
                for (int m = 0; m < 2; ++m)
                    #pragma unroll
                    for (int n = 0; n < 4; ++n)
                        acc[m][n] = __builtin_amdgcn_mfma_f32_16x16x32_bf16(af[k][kc][m], b[n], acc[m][n], 0, 0, 0);
            }
        }
    }
    #pragma unroll
    for (int m = 0; m < 2; ++m) {
        int cb = (w >> 1) * 32 + m * 16 + q4 * 4;
        float bv[4];
        #pragma unroll
        for (int r = 0; r < 4; ++r) bv[r] = bias[cb + r];
        #pragma unroll
        for (int n = 0; n < 4; ++n) {
            int lt = (w & 1) * 64 + n * 16 + lrow;
            #pragma unroll
            for (int r = 0; r < 4; ++r) {
                size_t a = (size_t)bn * 8192 + (size_t)(cb + r) * 128 + lt;
                y[a] = acc[m][n][r] + bv[r] + x2[a];
            }
        }
    }
}

// ---------- launch ----------
extern "C" void kernel_launch(void* const* d_in, const int* in_sizes, int n_in,
                              void* d_out, int out_size, void* d_ws, size_t ws_size,
                              hipStream_t stream) {
    (void)in_sizes; (void)n_in; (void)out_size;
    const float* x     = (const float*)d_in[0];
    const float* gn1_g = (const float*)d_in[1];
    const float* gn1_b = (const float*)d_in[2];
    const float* w_qkv = (const float*)d_in[3];
    const float* b_qkv = (const float*)d_in[4];
    const float* w_mg  = (const float*)d_in[5];
    const float* b_mg  = (const float*)d_in[6];
    const float* gn2_g = (const float*)d_in[7];
    const float* gn2_b = (const float*)d_in[8];
    const float* w_f1  = (const float*)d_in[9];
    const float* b_f1  = (const float*)d_in[10];
    const float* w_f2  = (const float*)d_in[11];
    const float* b_f2  = (const float*)d_in[12];
    float* y = (float*)d_out;

    char* ws = (char*)d_ws;
    const size_t OFF_SA1 = 0;
    const size_t OFF_SB1 = 131072;
    const size_t OFF_SA2 = 262144;
    const size_t OFF_SB2 = 393216;
    const size_t OFF_NQ  = 524288;
    const size_t OFF_NK  = 655360;
    const size_t OFF_WQ  = 786432;        // 589,824 B
    const size_t OFF_WMG = 1376256;       // 196,608 B
    const size_t OFF_WF1 = 1572864;       // 98,304 B
    const size_t OFF_WF2 = 1671168;       // 98,304 B
    const size_t OFF_X2  = 2097152;       // 16.78 MB -> ends 18,874,368
    const size_t OFF_XNT = 18874368;      // 8,519,680 B -> ends 27,394,048
    const size_t OFF_CHUNK = 27394048;
    const size_t H_BYTES = 33554432;

    int CH = 1;
    {
        const int cands[5] = {16, 8, 4, 2, 1};
        for (int ci = 0; ci < 5; ++ci) {
            int c = cands[ci];
            size_t qsz = (size_t)c * 4194304;
            size_t asz = (size_t)c * 1048576;
            size_t body = 3 * qsz + asz;
            if (body < H_BYTES) body = H_BYTES;
            if (OFF_CHUNK + body <= ws_size) { CH = c; break; }
        }
    }
    const size_t QSZ = (size_t)CH * 4194304;
    const size_t OFF_Q    = OFF_CHUNK;
    const size_t OFF_K    = OFF_Q + QSZ;
    const size_t OFF_V    = OFF_K + QSZ;
    const size_t OFF_ATTN = OFF_V + QSZ;

    float* sa1 = (float*)(ws + OFF_SA1);
    float* sb1 = (float*)(ws + OFF_SB1);
    float* sa2 = (float*)(ws + OFF_SA2);
    float* sb2 = (float*)(ws + OFF_SB2);
    float* nqp = (float*)(ws + OFF_NQ);
    float* nkp = (float*)(ws + OFF_NK);
    unsigned short* wqb  = (unsigned short*)(ws + OFF_WQ);
    unsigned short* wmgb = (unsigned short*)(ws + OFF_WMG);
    unsigned short* wf1b = (unsigned short*)(ws + OFF_WF1);
    unsigned short* wf2b = (unsigned short*)(ws + OFF_WF2);
    float* x2  = (float*)(ws + OFF_X2);
    unsigned short* xnt  = (unsigned short*)(ws + OFF_XNT);
    unsigned short* qb   = (unsigned short*)(ws + OFF_Q);
    unsigned short* kb   = (unsigned short*)(ws + OFF_K);
    unsigned short* vbuf = (unsigned short*)(ws + OFF_V);
    unsigned short* attn = (unsigned short*)(ws + OFF_ATTN);
    unsigned short* umat = (unsigned short*)(ws + OFF_Q);      // reuse q (dead after attnw)
    unsigned short* hbuf = (unsigned short*)(ws + OFF_CHUNK);  // reuse chunk region after loop

    gnstats_kernel<<<512, 256, 0, stream>>>(x, gn1_g, gn1_b, sa1, sb1);
    xprep_kernel<<<512, 256, 0, stream>>>(x, sa1, sb1, xnt);
    prep_w_kernel<<<384, 256, 0, stream>>>(w_qkv, wqb, 98304);
    prep_w_kernel<<<128, 256, 0, stream>>>(w_mg,  wmgb, 32768);
    prep_w_kernel<<<64,  256, 0, stream>>>(w_f1,  wf1b, 16384);
    prep_w_kernel<<<64,  256, 0, stream>>>(w_f2,  wf2b, 16384);
    const int nch = 16 / CH;
    for (int cidx = 0; cidx < nch; ++cidx) {
        int b0 = cidx * CH;
        conv_qkv_mfma<<<dim3(12, CH * 32), 256, 0, stream>>>(xnt, wqb, b_qkv, qb, kb, vbuf, nqp, nkp, b0);
        attnw_mfma<<<dim3(2, 2, CH * 8), 256, 0, stream>>>(qb, kb, nqp, nkp, attn);
        pv_mfma<<<dim3(8, 2, CH * 8), 256, 0, stream>>>(attn, vbuf, umat);
        merge_mfma<<<CH * 32, 256, 0, stream>>>(umat, x, wmgb, b_mg, x2, b0);
    }
    gnstats_kernel<<<512, 256, 0, stream>>>(x2, gn2_g, gn2_b, sa2, sb2);
    xprep_kernel<<<512, 256, 0, stream>>>(x2, sa2, sb2, xnt);
    ff1_mfma<<<dim3(2, 512), 256, 0, stream>>>(xnt, wf1b, b_f1, hbuf);
    ff2_mfma<<<512, 256, 0, stream>>>(hbuf, x2, wf2b, b_f2, y);
}